// Round 3
// baseline (1250.801 us; speedup 1.0000x reference)
//
#include <hip/hip_runtime.h>

#define DIM 128
#define ALPHA 0.1f
#define BETA 0.40546510810816438f  // log(0.5/1 + 1.0)

// K1: h = ALPHA * x0   (fuses the alpha-mix into the zero-init of the scatter target)
__global__ __launch_bounds__(256) void init_h(const float* __restrict__ x0,
                                              float* __restrict__ h, int total4) {
  int i = blockIdx.x * 256 + threadIdx.x;
  if (i < total4) {
    float4 v = ((const float4*)x0)[i];
    v.x *= ALPHA; v.y *= ALPHA; v.z *= ALPHA; v.w *= ALPHA;
    ((float4*)h)[i] = v;
  }
}

// K2: h[col[e]] += 0.9 * norm[e] * x[row[e]]   (32 threads per edge, float4 each)
__global__ __launch_bounds__(256) void scatter_edges(const float* __restrict__ x,
                                                     const int* __restrict__ row,
                                                     const int* __restrict__ col,
                                                     const float* __restrict__ nrm,
                                                     float* __restrict__ h, int E) {
  int gid = blockIdx.x * 256 + threadIdx.x;
  int e = gid >> 5;
  if (e >= E) return;
  int d4 = (gid & 31) << 2;
  int r = row[e];
  int c = col[e];
  float s = (1.0f - ALPHA) * nrm[e];
  const float4 v = *(const float4*)(x + (size_t)r * DIM + d4);
  float* dst = h + (size_t)c * DIM + d4;
  atomicAdd(dst + 0, s * v.x);
  atomicAdd(dst + 1, s * v.y);
  atomicAdd(dst + 2, s * v.z);
  atomicAdd(dst + 3, s * v.w);
}

// K3: out[n][j] = (1-BETA)*h[n][j] + BETA * sum_k h[n][k] * W[j][k]
// Thread j (= tid & 127) holds W row j in 32 float4 registers for the whole block.
// slot (= tid >> 7) selects which of 2 rows-in-flight this thread computes.
// Alias-safe for h == out: each global element is read only by the thread that writes it,
// and the dot uses the LDS-staged copy loaded before __syncthreads().
template <int ROWS>
__global__ __launch_bounds__(256) void final_mix(const float* __restrict__ h,
                                                 const float* __restrict__ W,
                                                 float* __restrict__ out, int nrows) {
  __shared__ float4 hrow[2][DIM / 4];
  const int tid = threadIdx.x;
  const int j = tid & (DIM - 1);
  const int slot = tid >> 7;

  float4 w[DIM / 4];
#pragma unroll
  for (int k4 = 0; k4 < DIM / 4; ++k4) w[k4] = ((const float4*)(W + (size_t)j * DIM))[k4];

  const int row0 = blockIdx.x * ROWS;
  for (int rr = 0; rr < ROWS; rr += 2) {
    // cooperative load of the 2 rows for this iteration (64 threads, 1 float4 each)
    if (tid < 2 * (DIM / 4)) {
      int which = tid >> 5;          // 0 or 1
      int k4 = tid & 31;
      int rload = row0 + rr + which;
      if (rload < nrows) hrow[which][k4] = ((const float4*)(h + (size_t)rload * DIM))[k4];
    }
    __syncthreads();

    const int r = row0 + rr + slot;
    if (r < nrows) {
      float acc = 0.0f;
      float hself = 0.0f;
#pragma unroll
      for (int k4 = 0; k4 < DIM / 4; ++k4) {
        float4 hv = hrow[slot][k4];
        acc += hv.x * w[k4].x + hv.y * w[k4].y + hv.z * w[k4].z + hv.w * w[k4].w;
        if (k4 == (j >> 2)) {
          hself = (j & 3) == 0 ? hv.x : (j & 3) == 1 ? hv.y : (j & 3) == 2 ? hv.z : hv.w;
        }
      }
      out[(size_t)r * DIM + j] = (1.0f - BETA) * hself + BETA * acc;
    }
    __syncthreads();
  }
}

extern "C" void kernel_launch(void* const* d_in, const int* in_sizes, int n_in,
                              void* d_out, int out_size, void* d_ws, size_t ws_size,
                              hipStream_t stream) {
  const float* x = (const float*)d_in[0];
  const float* x0 = (const float*)d_in[1];
  const int* ei = (const int*)d_in[2];
  const float* nrm = (const float*)d_in[3];
  const float* W = (const float*)d_in[4];
  float* out = (float*)d_out;

  const int N = in_sizes[0] / DIM;
  const int E = in_sizes[2] / 2;
  const int* row = ei;
  const int* col = ei + E;

  const size_t hbytes = (size_t)N * DIM * sizeof(float);
  float* h = (ws_size >= hbytes) ? (float*)d_ws : out;

  // K1: h = ALPHA * x0
  {
    int total4 = N * DIM / 4;
    int blocks = (total4 + 255) / 256;
    hipLaunchKernelGGL(init_h, dim3(blocks), dim3(256), 0, stream, x0, h, total4);
  }
  // K2: scatter-add edges
  {
    long long threads = (long long)E * 32;
    int blocks = (int)((threads + 255) / 256);
    hipLaunchKernelGGL(scatter_edges, dim3(blocks), dim3(256), 0, stream, x, row, col, nrm, h, E);
  }
  // K3: fused residual + linear
  {
    constexpr int ROWS = 32;
    int blocks = (N + ROWS - 1) / ROWS;
    hipLaunchKernelGGL(final_mix<ROWS>, dim3(blocks), dim3(256), 0, stream, h, W, out, N);
  }
}

// Round 7
// 342.105 us; speedup vs baseline: 3.6562x; 3.6562x over previous
//
#include <hip/hip_runtime.h>

#define DIM 128
#define ALPHA 0.1f
#define BETA 0.40546510810816438f  // log(0.5/1 + 1.0)

// ---------------- CSR build ----------------

__global__ __launch_bounds__(256) void count_edges(const int* __restrict__ col,
                                                   int* __restrict__ counts, int E) {
  int e = blockIdx.x * 256 + threadIdx.x;
  if (e < E) atomicAdd(&counts[col[e]], 1);
}

// per-block exclusive scan of counts -> offsets (local), block totals -> blockSums
__global__ __launch_bounds__(256) void scan_blocks(const int* __restrict__ counts,
                                                   int* __restrict__ offsets,
                                                   int* __restrict__ blockSums, int N) {
  __shared__ int sm[256];
  int tid = threadIdx.x;
  int gid = blockIdx.x * 256 + tid;
  int v = (gid < N) ? counts[gid] : 0;
  sm[tid] = v;
  __syncthreads();
  for (int off = 1; off < 256; off <<= 1) {
    int t = (tid >= off) ? sm[tid - off] : 0;
    __syncthreads();
    sm[tid] += t;
    __syncthreads();
  }
  if (gid < N) offsets[gid] = sm[tid] - v;  // local exclusive
  if (tid == 255) blockSums[blockIdx.x] = sm[255];
}

// exclusive scan of blockSums (nb <= 256), single block
__global__ __launch_bounds__(256) void scan_sums(int* __restrict__ blockSums, int nb) {
  __shared__ int sm[256];
  int tid = threadIdx.x;
  int v = (tid < nb) ? blockSums[tid] : 0;
  sm[tid] = v;
  __syncthreads();
  for (int off = 1; off < 256; off <<= 1) {
    int t = (tid >= off) ? sm[tid - off] : 0;
    __syncthreads();
    sm[tid] += t;
    __syncthreads();
  }
  if (tid < nb) blockSums[tid] = sm[tid] - v;  // exclusive
}

__global__ __launch_bounds__(256) void add_offsets(int* __restrict__ offsets,
                                                   const int* __restrict__ blockSums,
                                                   int N, int E) {
  int gid = blockIdx.x * 256 + threadIdx.x;
  if (gid < N) offsets[gid] += blockSums[gid >> 8];
  else if (gid == N) offsets[N] = E;
}

__global__ __launch_bounds__(256) void fill_edges(const int* __restrict__ row,
                                                  const int* __restrict__ col,
                                                  const float* __restrict__ nrm,
                                                  const int* __restrict__ offsets,
                                                  int* __restrict__ cursor,
                                                  int* __restrict__ srow,
                                                  float* __restrict__ sscale, int E) {
  int e = blockIdx.x * 256 + threadIdx.x;
  if (e >= E) return;
  int c = col[e];
  int p = atomicAdd(&cursor[c], 1);
  int idx = offsets[c] + p;
  srow[idx] = row[e];
  sscale[idx] = (1.0f - ALPHA) * nrm[e];
}

// ---------------- gather: h[n] = sum_e scale*x[row] + ALPHA*x0[n] ----------------
// one wave per node; lane holds dims {2*lane, 2*lane+1}; edge meta broadcast via shfl
__global__ __launch_bounds__(256) void gather_nodes(const float* __restrict__ x,
                                                    const float* __restrict__ x0,
                                                    const int* __restrict__ offs,
                                                    const int* __restrict__ srow,
                                                    const float* __restrict__ sscale,
                                                    float* __restrict__ h, int N) {
  int lane = threadIdx.x & 63;
  int gwave = blockIdx.x * 4 + (threadIdx.x >> 6);
  int nwaves = gridDim.x * 4;
  for (int n = gwave; n < N; n += nwaves) {
    int s = offs[n], t = offs[n + 1];
    float ax = 0.0f, ay = 0.0f;
    for (int base = s; base < t; base += 64) {
      int r = 0;
      float sc = 0.0f;
      if (base + lane < t) {
        r = srow[base + lane];
        sc = sscale[base + lane];
      }
      int cnt = t - base;
      if (cnt > 64) cnt = 64;
      for (int i = 0; i < cnt; ++i) {
        int ri = __shfl(r, i);
        float si = __shfl(sc, i);
        float2 v = *(const float2*)(x + (size_t)ri * DIM + 2 * lane);
        ax += si * v.x;
        ay += si * v.y;
      }
    }
    float2 v0 = *(const float2*)(x0 + (size_t)n * DIM + 2 * lane);
    float2 hv;
    hv.x = ax + ALPHA * v0.x;
    hv.y = ay + ALPHA * v0.y;
    *(float2*)(h + (size_t)n * DIM + 2 * lane) = hv;
  }
}

// ---------------- fallback scatter (atomic path, used only if ws too small) ----------
__global__ __launch_bounds__(256) void init_h(const float* __restrict__ x0,
                                              float* __restrict__ h, int total4) {
  int i = blockIdx.x * 256 + threadIdx.x;
  if (i < total4) {
    float4 v = ((const float4*)x0)[i];
    v.x *= ALPHA; v.y *= ALPHA; v.z *= ALPHA; v.w *= ALPHA;
    ((float4*)h)[i] = v;
  }
}

__global__ __launch_bounds__(256) void scatter_edges(const float* __restrict__ x,
                                                     const int* __restrict__ row,
                                                     const int* __restrict__ col,
                                                     const float* __restrict__ nrm,
                                                     float* __restrict__ h, int E) {
  int gid = blockIdx.x * 256 + threadIdx.x;
  int e = gid >> 5;
  if (e >= E) return;
  int d4 = (gid & 31) << 2;
  int r = row[e];
  int c = col[e];
  float s = (1.0f - ALPHA) * nrm[e];
  const float4 v = *(const float4*)(x + (size_t)r * DIM + d4);
  float* dst = h + (size_t)c * DIM + d4;
  atomicAdd(dst + 0, s * v.x);
  atomicAdd(dst + 1, s * v.y);
  atomicAdd(dst + 2, s * v.z);
  atomicAdd(dst + 3, s * v.w);
}

// ---------------- final: out = (1-B)*h + B*(h @ W^T), in-place safe (h may == out) ----
// 8 rows staged per sync (all 256 threads load), thread j holds W row j in 32 float4.
template <int ROWS>
__global__ __launch_bounds__(256) void final_mix8(const float* __restrict__ h,
                                                  const float* __restrict__ W,
                                                  float* __restrict__ out, int nrows) {
  __shared__ float4 hrow[8][DIM / 4];
  const int tid = threadIdx.x;
  const int j = tid & (DIM - 1);
  const int slot = tid >> 7;

  float4 w[DIM / 4];
#pragma unroll
  for (int k4 = 0; k4 < DIM / 4; ++k4) w[k4] = ((const float4*)(W + (size_t)j * DIM))[k4];

  const int row0 = blockIdx.x * ROWS;
  for (int rr = 0; rr < ROWS; rr += 8) {
    // stage 8 rows: thread t -> row (t>>5), k4 (t&31)
    {
      int which = tid >> 5;
      int k4 = tid & 31;
      int rload = row0 + rr + which;
      if (rload < nrows) hrow[which][k4] = ((const float4*)(h + (size_t)rload * DIM))[k4];
    }
    __syncthreads();
#pragma unroll
    for (int sub = 0; sub < 8; sub += 2) {
      int r = row0 + rr + sub + slot;
      if (r < nrows) {
        float acc = 0.0f;
        float hself = 0.0f;
#pragma unroll
        for (int k4 = 0; k4 < DIM / 4; ++k4) {
          float4 hv = hrow[sub + slot][k4];
          acc += hv.x * w[k4].x + hv.y * w[k4].y + hv.z * w[k4].z + hv.w * w[k4].w;
          if (k4 == (j >> 2)) {
            hself = (j & 3) == 0 ? hv.x : (j & 3) == 1 ? hv.y : (j & 3) == 2 ? hv.z : hv.w;
          }
        }
        out[(size_t)r * DIM + j] = (1.0f - BETA) * hself + BETA * acc;
      }
    }
    __syncthreads();
  }
}

extern "C" void kernel_launch(void* const* d_in, const int* in_sizes, int n_in,
                              void* d_out, int out_size, void* d_ws, size_t ws_size,
                              hipStream_t stream) {
  const float* x = (const float*)d_in[0];
  const float* x0 = (const float*)d_in[1];
  const int* ei = (const int*)d_in[2];
  const float* nrm = (const float*)d_in[3];
  const float* W = (const float*)d_in[4];
  float* out = (float*)d_out;

  const int N = in_sizes[0] / DIM;
  const int E = in_sizes[2] / 2;
  const int* row = ei;
  const int* col = ei + E;

  // ws layout: counts[N+1] | offsets[N+1] | blockSums[256] | srow[E] | sscale[E]
  const size_t need = (size_t)(2 * (N + 1) + 256 + 2 * E) * sizeof(int);

  constexpr int ROWS = 32;
  const int mixBlocks = (N + ROWS - 1) / ROWS;

  if (ws_size >= need) {
    int* counts = (int*)d_ws;
    int* offsets = counts + (N + 1);
    int* blockSums = offsets + (N + 1);
    int* srow = blockSums + 256;
    float* sscale = (float*)(srow + E);

    const int eBlocks = (E + 255) / 256;
    const int nBlocks = (N + 255) / 256;       // scan blocks over counts
    const int n1Blocks = (N + 256) / 256;      // covers N+1 entries for add_offsets

    hipMemsetAsync(counts, 0, (size_t)(N + 1) * sizeof(int), stream);
    hipLaunchKernelGGL(count_edges, dim3(eBlocks), dim3(256), 0, stream, col, counts, E);
    hipLaunchKernelGGL(scan_blocks, dim3(nBlocks), dim3(256), 0, stream, counts, offsets, blockSums, N);
    hipLaunchKernelGGL(scan_sums, dim3(1), dim3(256), 0, stream, blockSums, nBlocks);
    hipLaunchKernelGGL(add_offsets, dim3(n1Blocks), dim3(256), 0, stream, offsets, blockSums, N, E);
    hipMemsetAsync(counts, 0, (size_t)(N + 1) * sizeof(int), stream);  // reuse as cursor
    hipLaunchKernelGGL(fill_edges, dim3(eBlocks), dim3(256), 0, stream, row, col, nrm, offsets,
                       counts, srow, sscale, E);
    // gather writes h directly into out; final_mix8 is in-place safe
    const int gBlocks = (N + 3) / 4;
    hipLaunchKernelGGL(gather_nodes, dim3(gBlocks), dim3(256), 0, stream, x, x0, offsets, srow,
                       sscale, out, N);
    hipLaunchKernelGGL(final_mix8<ROWS>, dim3(mixBlocks), dim3(256), 0, stream, out, W, out, N);
  } else {
    // fallback: atomic scatter path (proven in round 3), h aliases out
    int total4 = N * DIM / 4;
    hipLaunchKernelGGL(init_h, dim3((total4 + 255) / 256), dim3(256), 0, stream, x0, out, total4);
    long long threads = (long long)E * 32;
    hipLaunchKernelGGL(scatter_edges, dim3((int)((threads + 255) / 256)), dim3(256), 0, stream, x,
                       row, col, nrm, out, E);
    hipLaunchKernelGGL(final_mix8<ROWS>, dim3(mixBlocks), dim3(256), 0, stream, out, W, out, N);
  }
}

// Round 8
// 153.415 us; speedup vs baseline: 8.1531x; 2.2299x over previous
//
#include <hip/hip_runtime.h>

#define DIM 128
#define ALPHA 0.1f
#define BETA 0.40546510810816438f  // log(0.5/1 + 1.0)

typedef __attribute__((ext_vector_type(8))) short short8v;  // 8 bf16 (4 VGPRs)
typedef __attribute__((ext_vector_type(4))) float float4v;  // MFMA acc

static __device__ inline short f2bf(float f) {
  union { float f; unsigned u; } a;
  a.f = f;
  unsigned r = a.u + 0x7fff + ((a.u >> 16) & 1);  // round-to-nearest-even
  return (short)(r >> 16);
}

// ---------------- CSR build ----------------

__global__ __launch_bounds__(256) void count_edges(const int* __restrict__ col,
                                                   int* __restrict__ counts, int E) {
  int e = blockIdx.x * 256 + threadIdx.x;
  if (e < E) atomicAdd(&counts[col[e]], 1);
}

__global__ __launch_bounds__(256) void scan_blocks(const int* __restrict__ counts,
                                                   int* __restrict__ offsets,
                                                   int* __restrict__ blockSums, int N) {
  __shared__ int sm[256];
  int tid = threadIdx.x;
  int gid = blockIdx.x * 256 + tid;
  int v = (gid < N) ? counts[gid] : 0;
  sm[tid] = v;
  __syncthreads();
  for (int off = 1; off < 256; off <<= 1) {
    int t = (tid >= off) ? sm[tid - off] : 0;
    __syncthreads();
    sm[tid] += t;
    __syncthreads();
  }
  if (gid < N) offsets[gid] = sm[tid] - v;
  if (tid == 255) blockSums[blockIdx.x] = sm[255];
}

__global__ __launch_bounds__(256) void scan_sums(int* __restrict__ blockSums, int nb) {
  __shared__ int sm[256];
  int tid = threadIdx.x;
  int v = (tid < nb) ? blockSums[tid] : 0;
  sm[tid] = v;
  __syncthreads();
  for (int off = 1; off < 256; off <<= 1) {
    int t = (tid >= off) ? sm[tid - off] : 0;
    __syncthreads();
    sm[tid] += t;
    __syncthreads();
  }
  if (tid < nb) blockSums[tid] = sm[tid] - v;
}

__global__ __launch_bounds__(256) void add_offsets(int* __restrict__ offsets,
                                                   const int* __restrict__ blockSums,
                                                   int N, int E) {
  int gid = blockIdx.x * 256 + threadIdx.x;
  if (gid < N) offsets[gid] += blockSums[gid >> 8];
  else if (gid == N) offsets[N] = E;
}

__global__ __launch_bounds__(256) void fill_edges(const int* __restrict__ row,
                                                  const int* __restrict__ col,
                                                  const float* __restrict__ nrm,
                                                  const int* __restrict__ offsets,
                                                  int* __restrict__ cursor,
                                                  int* __restrict__ srow,
                                                  float* __restrict__ sscale, int E) {
  int e = blockIdx.x * 256 + threadIdx.x;
  if (e >= E) return;
  int c = col[e];
  int p = atomicAdd(&cursor[c], 1);
  int idx = offsets[c] + p;
  srow[idx] = row[e];
  sscale[idx] = (1.0f - ALPHA) * nrm[e];
}

// ---------------- gather: h[n] = sum_e scale*x[row] + ALPHA*x0[n] ----------------
// one wave per node; 4-edge unroll with 8 independent accumulators for ILP/MLP.
// sc=0 padding makes the rounded-up iteration count exact (0*x contributes 0).
__global__ __launch_bounds__(256) void gather_nodes(const float* __restrict__ x,
                                                    const float* __restrict__ x0,
                                                    const int* __restrict__ offs,
                                                    const int* __restrict__ srow,
                                                    const float* __restrict__ sscale,
                                                    float* __restrict__ h, int N) {
  int lane = threadIdx.x & 63;
  int gwave = blockIdx.x * 4 + (threadIdx.x >> 6);
  int nwaves = gridDim.x * 4;
  int dbase = 2 * lane;
  for (int n = gwave; n < N; n += nwaves) {
    int s = offs[n], t = offs[n + 1];
    float ax = 0, ay = 0, bx = 0, by = 0, cx = 0, cy = 0, dx = 0, dy = 0;
    for (int base = s; base < t; base += 64) {
      int r = 0;
      float sc = 0.0f;
      if (base + lane < t) {
        r = srow[base + lane];
        sc = sscale[base + lane];
      }
      int cnt = t - base;
      if (cnt > 64) cnt = 64;
      int cnt4 = (cnt + 3) & ~3;
      for (int i = 0; i < cnt4; i += 4) {
        int r0 = __shfl(r, i), r1 = __shfl(r, i + 1);
        int r2 = __shfl(r, i + 2), r3 = __shfl(r, i + 3);
        float s0 = __shfl(sc, i), s1 = __shfl(sc, i + 1);
        float s2 = __shfl(sc, i + 2), s3 = __shfl(sc, i + 3);
        float2 v0 = *(const float2*)(x + (size_t)r0 * DIM + dbase);
        float2 v1 = *(const float2*)(x + (size_t)r1 * DIM + dbase);
        float2 v2 = *(const float2*)(x + (size_t)r2 * DIM + dbase);
        float2 v3 = *(const float2*)(x + (size_t)r3 * DIM + dbase);
        ax += s0 * v0.x; ay += s0 * v0.y;
        bx += s1 * v1.x; by += s1 * v1.y;
        cx += s2 * v2.x; cy += s2 * v2.y;
        dx += s3 * v3.x; dy += s3 * v3.y;
      }
    }
    float2 v0 = *(const float2*)(x0 + (size_t)n * DIM + dbase);
    float2 hv;
    hv.x = ((ax + bx) + (cx + dx)) + ALPHA * v0.x;
    hv.y = ((ay + by) + (cy + dy)) + ALPHA * v0.y;
    *(float2*)(h + (size_t)n * DIM + dbase) = hv;
  }
}

// ---------------- fallback scatter (atomic path, used only if ws too small) ----------
__global__ __launch_bounds__(256) void init_h(const float* __restrict__ x0,
                                              float* __restrict__ h, int total4) {
  int i = blockIdx.x * 256 + threadIdx.x;
  if (i < total4) {
    float4 v = ((const float4*)x0)[i];
    v.x *= ALPHA; v.y *= ALPHA; v.z *= ALPHA; v.w *= ALPHA;
    ((float4*)h)[i] = v;
  }
}

__global__ __launch_bounds__(256) void scatter_edges(const float* __restrict__ x,
                                                     const int* __restrict__ row,
                                                     const int* __restrict__ col,
                                                     const float* __restrict__ nrm,
                                                     float* __restrict__ h, int E) {
  int gid = blockIdx.x * 256 + threadIdx.x;
  int e = gid >> 5;
  if (e >= E) return;
  int d4 = (gid & 31) << 2;
  int r = row[e];
  int c = col[e];
  float s = (1.0f - ALPHA) * nrm[e];
  const float4 v = *(const float4*)(x + (size_t)r * DIM + d4);
  float* dst = h + (size_t)c * DIM + d4;
  atomicAdd(dst + 0, s * v.x);
  atomicAdd(dst + 1, s * v.y);
  atomicAdd(dst + 2, s * v.z);
  atomicAdd(dst + 3, s * v.w);
}

// ---------------- final: out = (1-B)*h + B*(h @ W^T) via bf16 MFMA, in-place ----------
// h lives in `out` (f32). Block: 64 rows x 128 cols. W and h-tile staged bf16 in LDS
// (+8-short row pad -> 2-way bank aliasing only). Wave w computes rows [16w,16w+16).
// mfma_f32_16x16x32_bf16 frags: A lane: row=l&15, k=(l>>4)*8+i (contig 16B);
// B lane: col=l&15, k=(l>>4)*8+i; D lane: col=l&15, row=(l>>4)*4+reg.
// Epilogue re-reads h as f32 from global for the exact residual; strict per-lane
// element ownership makes the in-place read-then-write safe.
__global__ __launch_bounds__(256) void final_mfma(const float* __restrict__ W,
                                                  float* __restrict__ out, int N) {
  __shared__ short W_s[128][136];
  __shared__ short h_s[64][136];
  const int tid = threadIdx.x;
  const int lane = tid & 63;
  const int wave = tid >> 6;
  const int row0 = blockIdx.x * 64;

  // stage W: 128x128 f32 -> bf16 LDS (float4 reads, short4 LDS writes)
  for (int idx = tid; idx < 128 * 32; idx += 256) {
    int r = idx >> 5, c4 = idx & 31;
    float4 v = ((const float4*)(W + (size_t)r * DIM))[c4];
    short4 sv = make_short4(f2bf(v.x), f2bf(v.y), f2bf(v.z), f2bf(v.w));
    *(short4*)&W_s[r][c4 * 4] = sv;
  }
  // stage h tile: 64x128 f32 (from out) -> bf16 LDS; zero-fill past N
  for (int idx = tid; idx < 64 * 32; idx += 256) {
    int r = idx >> 5, c4 = idx & 31;
    int R = row0 + r;
    short4 sv;
    if (R < N) {
      float4 v = ((const float4*)(out + (size_t)R * DIM))[c4];
      sv = make_short4(f2bf(v.x), f2bf(v.y), f2bf(v.z), f2bf(v.w));
    } else {
      sv = make_short4(0, 0, 0, 0);
    }
    *(short4*)&h_s[r][c4 * 4] = sv;
  }
  __syncthreads();

  const int wr0 = wave * 16;          // wave's row base within tile
  const int arow = wr0 + (lane & 15); // A-frag row for this lane
  const int kg = (lane >> 4) * 8;     // k sub-offset for this lane

  short8v a[4];
#pragma unroll
  for (int s = 0; s < 4; ++s) a[s] = *(const short8v*)&h_s[arow][s * 32 + kg];

#pragma unroll
  for (int jt = 0; jt < 8; ++jt) {
    const int bcol = jt * 16 + (lane & 15);
    float4v acc = {0.0f, 0.0f, 0.0f, 0.0f};
#pragma unroll
    for (int s = 0; s < 4; ++s) {
      short8v b = *(const short8v*)&W_s[bcol][s * 32 + kg];
      acc = __builtin_amdgcn_mfma_f32_16x16x32_bf16(a[s], b, acc, 0, 0, 0);
    }
    const int rbase = row0 + wr0 + ((lane >> 4) << 2);
#pragma unroll
    for (int p = 0; p < 4; ++p) {
      int R = rbase + p;
      if (R < N) {
        size_t off = (size_t)R * DIM + jt * 16 + (lane & 15);
        out[off] = (1.0f - BETA) * out[off] + BETA * acc[p];
      }
    }
  }
}

extern "C" void kernel_launch(void* const* d_in, const int* in_sizes, int n_in,
                              void* d_out, int out_size, void* d_ws, size_t ws_size,
                              hipStream_t stream) {
  const float* x = (const float*)d_in[0];
  const float* x0 = (const float*)d_in[1];
  const int* ei = (const int*)d_in[2];
  const float* nrm = (const float*)d_in[3];
  const float* W = (const float*)d_in[4];
  float* out = (float*)d_out;

  const int N = in_sizes[0] / DIM;
  const int E = in_sizes[2] / 2;
  const int* row = ei;
  const int* col = ei + E;

  // ws layout: counts[N+1] | offsets[N+1] | blockSums[256] | srow[E] | sscale[E]
  const size_t need = (size_t)(2 * (N + 1) + 256 + 2 * E) * sizeof(int);
  const int gemmBlocks = (N + 63) / 64;

  if (ws_size >= need) {
    int* counts = (int*)d_ws;
    int* offsets = counts + (N + 1);
    int* blockSums = offsets + (N + 1);
    int* srow = blockSums + 256;
    float* sscale = (float*)(srow + E);

    const int eBlocks = (E + 255) / 256;
    const int nBlocks = (N + 255) / 256;
    const int n1Blocks = (N + 256) / 256;

    hipMemsetAsync(counts, 0, (size_t)(N + 1) * sizeof(int), stream);
    hipLaunchKernelGGL(count_edges, dim3(eBlocks), dim3(256), 0, stream, col, counts, E);
    hipLaunchKernelGGL(scan_blocks, dim3(nBlocks), dim3(256), 0, stream, counts, offsets, blockSums, N);
    hipLaunchKernelGGL(scan_sums, dim3(1), dim3(256), 0, stream, blockSums, nBlocks);
    hipLaunchKernelGGL(add_offsets, dim3(n1Blocks), dim3(256), 0, stream, offsets, blockSums, N, E);
    hipMemsetAsync(counts, 0, (size_t)(N + 1) * sizeof(int), stream);  // reuse as cursor
    hipLaunchKernelGGL(fill_edges, dim3(eBlocks), dim3(256), 0, stream, row, col, nrm, offsets,
                       counts, srow, sscale, E);
    const int gBlocks = (N + 3) / 4;
    hipLaunchKernelGGL(gather_nodes, dim3(gBlocks), dim3(256), 0, stream, x, x0, offsets, srow,
                       sscale, out, N);
    hipLaunchKernelGGL(final_mfma, dim3(gemmBlocks), dim3(256), 0, stream, W, out, N);
  } else {
    // fallback: atomic scatter path (proven in round 3), h aliases out
    int total4 = N * DIM / 4;
    hipLaunchKernelGGL(init_h, dim3((total4 + 255) / 256), dim3(256), 0, stream, x0, out, total4);
    long long threads = (long long)E * 32;
    hipLaunchKernelGGL(scatter_edges, dim3((int)((threads + 255) / 256)), dim3(256), 0, stream, x,
                       row, col, nrm, out, E);
    hipLaunchKernelGGL(final_mfma, dim3(gemmBlocks), dim3(256), 0, stream, W, out, N);
  }
}

// Round 9
// 149.349 us; speedup vs baseline: 8.3750x; 1.0272x over previous
//
#include <hip/hip_runtime.h>

#define DIM 128
#define ALPHA 0.1f
#define BETA 0.40546510810816438f  // log(0.5/1 + 1.0)

typedef __attribute__((ext_vector_type(8))) short short8v;  // 8 bf16 (4 VGPRs)
typedef __attribute__((ext_vector_type(4))) float float4v;  // MFMA acc

static __device__ inline short f2bf(float f) {
  union { float f; unsigned u; } a;
  a.f = f;
  unsigned r = a.u + 0x7fff + ((a.u >> 16) & 1);  // round-to-nearest-even
  return (short)(r >> 16);
}

// ---------------- CSR build ----------------

__global__ __launch_bounds__(256) void count_edges(const int* __restrict__ col,
                                                   int* __restrict__ counts, int E) {
  int e = blockIdx.x * 256 + threadIdx.x;
  if (e < E) atomicAdd(&counts[col[e]], 1);
}

__global__ __launch_bounds__(256) void scan_blocks(const int* __restrict__ counts,
                                                   int* __restrict__ offsets,
                                                   int* __restrict__ blockSums, int N) {
  __shared__ int sm[256];
  int tid = threadIdx.x;
  int gid = blockIdx.x * 256 + tid;
  int v = (gid < N) ? counts[gid] : 0;
  sm[tid] = v;
  __syncthreads();
  for (int off = 1; off < 256; off <<= 1) {
    int t = (tid >= off) ? sm[tid - off] : 0;
    __syncthreads();
    sm[tid] += t;
    __syncthreads();
  }
  if (gid < N) offsets[gid] = sm[tid] - v;
  if (tid == 255) blockSums[blockIdx.x] = sm[255];
}

__global__ __launch_bounds__(256) void scan_sums(int* __restrict__ blockSums, int nb) {
  __shared__ int sm[256];
  int tid = threadIdx.x;
  int v = (tid < nb) ? blockSums[tid] : 0;
  sm[tid] = v;
  __syncthreads();
  for (int off = 1; off < 256; off <<= 1) {
    int t = (tid >= off) ? sm[tid - off] : 0;
    __syncthreads();
    sm[tid] += t;
    __syncthreads();
  }
  if (tid < nb) blockSums[tid] = sm[tid] - v;
}

__global__ __launch_bounds__(256) void add_offsets(int* __restrict__ offsets,
                                                   const int* __restrict__ blockSums,
                                                   int N, int E) {
  int gid = blockIdx.x * 256 + threadIdx.x;
  if (gid < N) offsets[gid] += blockSums[gid >> 8];
  else if (gid == N) offsets[N] = E;
}

// packed (row, scale) per edge: one 8B store, one 8B load in gather
__global__ __launch_bounds__(256) void fill_edges(const int* __restrict__ row,
                                                  const int* __restrict__ col,
                                                  const float* __restrict__ nrm,
                                                  const int* __restrict__ offsets,
                                                  int* __restrict__ cursor,
                                                  int2* __restrict__ emeta, int E) {
  int e = blockIdx.x * 256 + threadIdx.x;
  if (e >= E) return;
  int c = col[e];
  int p = atomicAdd(&cursor[c], 1);
  int idx = offsets[c] + p;
  float s = (1.0f - ALPHA) * nrm[e];
  emeta[idx] = make_int2(row[e], __float_as_int(s));
}

// x f32 -> bf16 table (halves gather bytes; doubles effective L2 capacity for x)
__global__ __launch_bounds__(256) void convert_x(const float* __restrict__ x,
                                                 short* __restrict__ xb, int total4) {
  int i = blockIdx.x * 256 + threadIdx.x;
  if (i < total4) {
    float4 v = ((const float4*)x)[i];
    short4 sv = make_short4(f2bf(v.x), f2bf(v.y), f2bf(v.z), f2bf(v.w));
    ((short4*)xb)[i] = sv;
  }
}

// ---------------- gather: h[n] = sum_e scale*x[row] + ALPHA*x0[n] ----------------
// one wave per node; lane holds dims {2*lane, 2*lane+1}; 8-edge unroll, 8 indep chains.
// USE_BF: x is bf16 (uint per lane = 2 dims); else f32 (float2 per lane).
template <bool USE_BF>
__global__ __launch_bounds__(256) void gather_nodes(const void* __restrict__ xv,
                                                    const float* __restrict__ x0,
                                                    const int* __restrict__ offs,
                                                    const int2* __restrict__ emeta,
                                                    float* __restrict__ h, int N) {
  const unsigned* xb = (const unsigned*)xv;
  const float* xf = (const float*)xv;
  int lane = threadIdx.x & 63;
  int gwave = blockIdx.x * 4 + (threadIdx.x >> 6);
  int nwaves = gridDim.x * 4;
  int dbase = 2 * lane;
  for (int n = gwave; n < N; n += nwaves) {
    int s = offs[n], t = offs[n + 1];
    float accx[8], accy[8];
#pragma unroll
    for (int j = 0; j < 8; ++j) { accx[j] = 0.0f; accy[j] = 0.0f; }
    for (int base = s; base < t; base += 64) {
      int r = 0;
      float sc = 0.0f;
      if (base + lane < t) {
        int2 m = emeta[base + lane];
        r = m.x;
        sc = __int_as_float(m.y);
      }
      int cnt = t - base;
      if (cnt > 64) cnt = 64;
      int cnt8 = (cnt + 7) & ~7;
      for (int i = 0; i < cnt8; i += 8) {
#pragma unroll
        for (int j = 0; j < 8; ++j) {
          int rj = __shfl(r, i + j);
          float sj = __shfl(sc, i + j);
          float lo, hi;
          if (USE_BF) {
            unsigned u = xb[(size_t)rj * (DIM / 2) + lane];
            lo = __uint_as_float(u << 16);
            hi = __uint_as_float(u & 0xffff0000u);
          } else {
            float2 v = *(const float2*)(xf + (size_t)rj * DIM + dbase);
            lo = v.x;
            hi = v.y;
          }
          accx[j] += sj * lo;
          accy[j] += sj * hi;
        }
      }
    }
    float sx = ((accx[0] + accx[1]) + (accx[2] + accx[3])) +
               ((accx[4] + accx[5]) + (accx[6] + accx[7]));
    float sy = ((accy[0] + accy[1]) + (accy[2] + accy[3])) +
               ((accy[4] + accy[5]) + (accy[6] + accy[7]));
    float2 v0 = *(const float2*)(x0 + (size_t)n * DIM + dbase);
    float2 hv;
    hv.x = sx + ALPHA * v0.x;
    hv.y = sy + ALPHA * v0.y;
    *(float2*)(h + (size_t)n * DIM + dbase) = hv;
  }
}

// ---------------- fallback scatter (atomic path, used only if ws too small) ----------
__global__ __launch_bounds__(256) void init_h(const float* __restrict__ x0,
                                              float* __restrict__ h, int total4) {
  int i = blockIdx.x * 256 + threadIdx.x;
  if (i < total4) {
    float4 v = ((const float4*)x0)[i];
    v.x *= ALPHA; v.y *= ALPHA; v.z *= ALPHA; v.w *= ALPHA;
    ((float4*)h)[i] = v;
  }
}

__global__ __launch_bounds__(256) void scatter_edges(const float* __restrict__ x,
                                                     const int* __restrict__ row,
                                                     const int* __restrict__ col,
                                                     const float* __restrict__ nrm,
                                                     float* __restrict__ h, int E) {
  int gid = blockIdx.x * 256 + threadIdx.x;
  int e = gid >> 5;
  if (e >= E) return;
  int d4 = (gid & 31) << 2;
  int r = row[e];
  int c = col[e];
  float s = (1.0f - ALPHA) * nrm[e];
  const float4 v = *(const float4*)(x + (size_t)r * DIM + d4);
  float* dst = h + (size_t)c * DIM + d4;
  atomicAdd(dst + 0, s * v.x);
  atomicAdd(dst + 1, s * v.y);
  atomicAdd(dst + 2, s * v.z);
  atomicAdd(dst + 3, s * v.w);
}

// ---------------- final: out = (1-B)*h + B*(h @ W^T) via bf16 MFMA, in-place ----------
__global__ __launch_bounds__(256) void final_mfma(const float* __restrict__ W,
                                                  float* __restrict__ out, int N) {
  __shared__ short W_s[128][136];
  __shared__ short h_s[64][136];
  const int tid = threadIdx.x;
  const int lane = tid & 63;
  const int wave = tid >> 6;
  const int row0 = blockIdx.x * 64;

  for (int idx = tid; idx < 128 * 32; idx += 256) {
    int r = idx >> 5, c4 = idx & 31;
    float4 v = ((const float4*)(W + (size_t)r * DIM))[c4];
    short4 sv = make_short4(f2bf(v.x), f2bf(v.y), f2bf(v.z), f2bf(v.w));
    *(short4*)&W_s[r][c4 * 4] = sv;
  }
  for (int idx = tid; idx < 64 * 32; idx += 256) {
    int r = idx >> 5, c4 = idx & 31;
    int R = row0 + r;
    short4 sv;
    if (R < N) {
      float4 v = ((const float4*)(out + (size_t)R * DIM))[c4];
      sv = make_short4(f2bf(v.x), f2bf(v.y), f2bf(v.z), f2bf(v.w));
    } else {
      sv = make_short4(0, 0, 0, 0);
    }
    *(short4*)&h_s[r][c4 * 4] = sv;
  }
  __syncthreads();

  const int wr0 = wave * 16;
  const int arow = wr0 + (lane & 15);
  const int kg = (lane >> 4) * 8;

  short8v a[4];
#pragma unroll
  for (int s = 0; s < 4; ++s) a[s] = *(const short8v*)&h_s[arow][s * 32 + kg];

#pragma unroll
  for (int jt = 0; jt < 8; ++jt) {
    const int bcol = jt * 16 + (lane & 15);
    float4v acc = {0.0f, 0.0f, 0.0f, 0.0f};
#pragma unroll
    for (int s = 0; s < 4; ++s) {
      short8v b = *(const short8v*)&W_s[bcol][s * 32 + kg];
      acc = __builtin_amdgcn_mfma_f32_16x16x32_bf16(a[s], b, acc, 0, 0, 0);
    }
    const int rbase = row0 + wr0 + ((lane >> 4) << 2);
#pragma unroll
    for (int p = 0; p < 4; ++p) {
      int R = rbase + p;
      if (R < N) {
        size_t off = (size_t)R * DIM + jt * 16 + (lane & 15);
        out[off] = (1.0f - BETA) * out[off] + BETA * acc[p];
      }
    }
  }
}

extern "C" void kernel_launch(void* const* d_in, const int* in_sizes, int n_in,
                              void* d_out, int out_size, void* d_ws, size_t ws_size,
                              hipStream_t stream) {
  const float* x = (const float*)d_in[0];
  const float* x0 = (const float*)d_in[1];
  const int* ei = (const int*)d_in[2];
  const float* nrm = (const float*)d_in[3];
  const float* W = (const float*)d_in[4];
  float* out = (float*)d_out;

  const int N = in_sizes[0] / DIM;
  const int E = in_sizes[2] / 2;
  const int* row = ei;
  const int* col = ei + E;

  // ws layout: counts[N+1] | offsets[N+1] | blockSums[256] | emeta int2[E] | xb bf16[N*DIM]
  const size_t csrNeed = (size_t)(2 * (N + 1) + 256) * sizeof(int) + (size_t)E * 8;
  const size_t fullNeed = csrNeed + (size_t)N * DIM * sizeof(short);
  const int gemmBlocks = (N + 63) / 64;

  if (ws_size >= csrNeed) {
    int* counts = (int*)d_ws;
    int* offsets = counts + (N + 1);
    int* blockSums = offsets + (N + 1);
    int2* emeta = (int2*)(blockSums + 256);
    short* xb = (short*)(emeta + E);

    const int eBlocks = (E + 255) / 256;
    const int nBlocks = (N + 255) / 256;
    const int n1Blocks = (N + 256) / 256;

    hipMemsetAsync(counts, 0, (size_t)(N + 1) * sizeof(int), stream);
    hipLaunchKernelGGL(count_edges, dim3(eBlocks), dim3(256), 0, stream, col, counts, E);
    hipLaunchKernelGGL(scan_blocks, dim3(nBlocks), dim3(256), 0, stream, counts, offsets, blockSums, N);
    hipLaunchKernelGGL(scan_sums, dim3(1), dim3(256), 0, stream, blockSums, nBlocks);
    hipLaunchKernelGGL(add_offsets, dim3(n1Blocks), dim3(256), 0, stream, offsets, blockSums, N, E);
    hipMemsetAsync(counts, 0, (size_t)(N + 1) * sizeof(int), stream);  // reuse as cursor
    hipLaunchKernelGGL(fill_edges, dim3(eBlocks), dim3(256), 0, stream, row, col, nrm, offsets,
                       counts, emeta, E);
    const int gBlocks = (N + 3) / 4;
    if (ws_size >= fullNeed) {
      int total4 = N * DIM / 4;
      hipLaunchKernelGGL(convert_x, dim3((total4 + 255) / 256), dim3(256), 0, stream, x, xb, total4);
      hipLaunchKernelGGL(gather_nodes<true>, dim3(gBlocks), dim3(256), 0, stream, (const void*)xb,
                         x0, offsets, emeta, out, N);
    } else {
      hipLaunchKernelGGL(gather_nodes<false>, dim3(gBlocks), dim3(256), 0, stream, (const void*)x,
                         x0, offsets, emeta, out, N);
    }
    hipLaunchKernelGGL(final_mfma, dim3(gemmBlocks), dim3(256), 0, stream, W, out, N);
  } else {
    // fallback: atomic scatter path, h aliases out
    int total4 = N * DIM / 4;
    hipLaunchKernelGGL(init_h, dim3((total4 + 255) / 256), dim3(256), 0, stream, x0, out, total4);
    long long threads = (long long)E * 32;
    hipLaunchKernelGGL(scatter_edges, dim3((int)((threads + 255) / 256)), dim3(256), 0, stream, x,
                       row, col, nrm, out, E);
    hipLaunchKernelGGL(final_mfma, dim3(gemmBlocks), dim3(256), 0, stream, W, out, N);
  }
}

// Round 10
// 132.786 us; speedup vs baseline: 9.4197x; 1.1247x over previous
//
#include <hip/hip_runtime.h>

#define DIM 128
#define ALPHA 0.1f
#define BETA 0.40546510810816438f  // log(0.5/1 + 1.0)

typedef __attribute__((ext_vector_type(8))) short short8v;  // 8 bf16 (4 VGPRs)
typedef __attribute__((ext_vector_type(4))) float float4v;  // MFMA acc

static __device__ inline unsigned short f2bf(float f) {
  union { float f; unsigned u; } a;
  a.f = f;
  unsigned r = a.u + 0x7fff + ((a.u >> 16) & 1);  // round-to-nearest-even
  return (unsigned short)(r >> 16);
}

// ---------------- CSR build ----------------

__global__ __launch_bounds__(256) void count_edges(const int* __restrict__ col,
                                                   int* __restrict__ counts, int E) {
  int e = blockIdx.x * 256 + threadIdx.x;
  if (e < E) atomicAdd(&counts[col[e]], 1);
}

__global__ __launch_bounds__(256) void scan_blocks(const int* __restrict__ counts,
                                                   int* __restrict__ offsets,
                                                   int* __restrict__ blockSums, int N) {
  __shared__ int sm[256];
  int tid = threadIdx.x;
  int gid = blockIdx.x * 256 + tid;
  int v = (gid < N) ? counts[gid] : 0;
  sm[tid] = v;
  __syncthreads();
  for (int off = 1; off < 256; off <<= 1) {
    int t = (tid >= off) ? sm[tid - off] : 0;
    __syncthreads();
    sm[tid] += t;
    __syncthreads();
  }
  if (gid < N) offsets[gid] = sm[tid] - v;
  if (tid == 255) blockSums[blockIdx.x] = sm[255];
}

__global__ __launch_bounds__(256) void scan_sums(int* __restrict__ blockSums, int nb) {
  __shared__ int sm[256];
  int tid = threadIdx.x;
  int v = (tid < nb) ? blockSums[tid] : 0;
  sm[tid] = v;
  __syncthreads();
  for (int off = 1; off < 256; off <<= 1) {
    int t = (tid >= off) ? sm[tid - off] : 0;
    __syncthreads();
    sm[tid] += t;
    __syncthreads();
  }
  if (tid < nb) blockSums[tid] = sm[tid] - v;
}

__global__ __launch_bounds__(256) void add_offsets(int* __restrict__ offsets,
                                                   const int* __restrict__ blockSums,
                                                   int N, int E) {
  int gid = blockIdx.x * 256 + threadIdx.x;
  if (gid < N) offsets[gid] += blockSums[gid >> 8];
  else if (gid == N) offsets[N] = E;
}

// packed (row, scale) per edge: one 8B store, one 8B load in gather
__global__ __launch_bounds__(256) void fill_edges(const int* __restrict__ row,
                                                  const int* __restrict__ col,
                                                  const float* __restrict__ nrm,
                                                  const int* __restrict__ offsets,
                                                  int* __restrict__ cursor,
                                                  int2* __restrict__ emeta, int E) {
  int e = blockIdx.x * 256 + threadIdx.x;
  if (e >= E) return;
  int c = col[e];
  int p = atomicAdd(&cursor[c], 1);
  int idx = offsets[c] + p;
  float s = (1.0f - ALPHA) * nrm[e];
  emeta[idx] = make_int2(row[e], __float_as_int(s));
}

// x f32 -> bf16 table (halves gather bytes)
__global__ __launch_bounds__(256) void convert_x(const float* __restrict__ x,
                                                 short* __restrict__ xb, int total4) {
  int i = blockIdx.x * 256 + threadIdx.x;
  if (i < total4) {
    float4 v = ((const float4*)x)[i];
    short4 sv = make_short4((short)f2bf(v.x), (short)f2bf(v.y), (short)f2bf(v.z),
                            (short)f2bf(v.w));
    ((short4*)xb)[i] = sv;
  }
}

// W f32 -> bf16 table [128][128] row-major (32KB, L2-resident everywhere)
__global__ __launch_bounds__(256) void convert_w(const float* __restrict__ W,
                                                 short* __restrict__ Wb) {
  int i = blockIdx.x * 256 + threadIdx.x;  // 4096 float4s
  if (i < 128 * 32) {
    float4 v = ((const float4*)W)[i];
    short4 sv = make_short4((short)f2bf(v.x), (short)f2bf(v.y), (short)f2bf(v.z),
                            (short)f2bf(v.w));
    ((short4*)Wb)[i] = sv;
  }
}

// ---------------- fused gather + GEMM ----------------
// Block = 16 nodes (one MFMA row-tile), 4 waves. Wave w gathers local rows
// [4w, 4w+4) into a bf16 LDS tile hb[16][136], then all waves run the
// 16x128 @ 128x128^T MFMA with B-frags from global bf16 W (L2-resident).
// out[R][c] = (1-BETA)*bf16(h[R][c]) + BETA*acc. One global write, no h round-trip.
// MFMA frags (HW-validated in rounds 8/9): A row=l&15, k=(l>>4)*8+i;
// B col=l&15, same k; D col=l&15, row=(l>>4)*4+reg.
__global__ __launch_bounds__(256) void gather_gemm(const unsigned* __restrict__ xb,
                                                   const float* __restrict__ x0,
                                                   const int* __restrict__ offs,
                                                   const int2* __restrict__ emeta,
                                                   const short* __restrict__ Wb,
                                                   float* __restrict__ out, int N) {
  __shared__ unsigned short hb[16][136];
  const int tid = threadIdx.x;
  const int lane = tid & 63;
  const int wave = tid >> 6;
  const int row0 = blockIdx.x * 16;

  // ---- phase 1: gather 4 nodes per wave ----
  for (int q = 0; q < 4; ++q) {
    const int lr = wave * 4 + q;
    const int n = row0 + lr;
    unsigned packed = 0;
    if (n < N) {
      int s = offs[n], t = offs[n + 1];
      float accx[8], accy[8];
#pragma unroll
      for (int j = 0; j < 8; ++j) { accx[j] = 0.0f; accy[j] = 0.0f; }
      for (int base = s; base < t; base += 64) {
        int r = 0;
        float sc = 0.0f;
        if (base + lane < t) {
          int2 m = emeta[base + lane];
          r = m.x;
          sc = __int_as_float(m.y);
        }
        int cnt = t - base;
        if (cnt > 64) cnt = 64;
        int cnt8 = (cnt + 7) & ~7;
        for (int i = 0; i < cnt8; i += 8) {
#pragma unroll
          for (int j = 0; j < 8; ++j) {
            int rj = __shfl(r, i + j);
            float sj = __shfl(sc, i + j);
            unsigned u = xb[(size_t)rj * (DIM / 2) + lane];
            accx[j] += sj * __uint_as_float(u << 16);
            accy[j] += sj * __uint_as_float(u & 0xffff0000u);
          }
        }
      }
      float sx = ((accx[0] + accx[1]) + (accx[2] + accx[3])) +
                 ((accx[4] + accx[5]) + (accx[6] + accx[7]));
      float sy = ((accy[0] + accy[1]) + (accy[2] + accy[3])) +
                 ((accy[4] + accy[5]) + (accy[6] + accy[7]));
      float2 v0 = *(const float2*)(x0 + (size_t)n * DIM + 2 * lane);
      float hx = sx + ALPHA * v0.x;
      float hy = sy + ALPHA * v0.y;
      packed = (unsigned)f2bf(hx) | ((unsigned)f2bf(hy) << 16);
    }
    *(unsigned*)&hb[lr][2 * lane] = packed;
  }
  __syncthreads();

  // ---- phase 2: MFMA on the 16-row tile; wave w owns column tiles {2w, 2w+1} ----
  const int arow = lane & 15;
  const int kg = (lane >> 4) * 8;
  short8v a[4];
#pragma unroll
  for (int s = 0; s < 4; ++s) a[s] = *(const short8v*)&hb[arow][s * 32 + kg];

#pragma unroll
  for (int j2 = 0; j2 < 2; ++j2) {
    const int jt = wave * 2 + j2;
    const int bcol = jt * 16 + (lane & 15);
    float4v acc = {0.0f, 0.0f, 0.0f, 0.0f};
#pragma unroll
    for (int s = 0; s < 4; ++s) {
      short8v b = *(const short8v*)(Wb + (size_t)bcol * DIM + s * 32 + kg);
      acc = __builtin_amdgcn_mfma_f32_16x16x32_bf16(a[s], b, acc, 0, 0, 0);
    }
    const int lr0 = (lane >> 4) << 2;
#pragma unroll
    for (int p = 0; p < 4; ++p) {
      int R = row0 + lr0 + p;
      if (R < N) {
        int c = jt * 16 + (lane & 15);
        float hv = __uint_as_float(((unsigned)hb[lr0 + p][c]) << 16);
        out[(size_t)R * DIM + c] = (1.0f - BETA) * hv + BETA * acc[p];
      }
    }
  }
}

// ---------------- mid-tier: unfused f32 gather (proven round 7) ----------------
__global__ __launch_bounds__(256) void gather_nodes_f32(const float* __restrict__ x,
                                                        const float* __restrict__ x0,
                                                        const int* __restrict__ offs,
                                                        const int2* __restrict__ emeta,
                                                        float* __restrict__ h, int N) {
  int lane = threadIdx.x & 63;
  int gwave = blockIdx.x * 4 + (threadIdx.x >> 6);
  int nwaves = gridDim.x * 4;
  int dbase = 2 * lane;
  for (int n = gwave; n < N; n += nwaves) {
    int s = offs[n], t = offs[n + 1];
    float ax = 0, ay = 0, bx = 0, by = 0, cx = 0, cy = 0, dx = 0, dy = 0;
    for (int base = s; base < t; base += 64) {
      int r = 0;
      float sc = 0.0f;
      if (base + lane < t) {
        int2 m = emeta[base + lane];
        r = m.x;
        sc = __int_as_float(m.y);
      }
      int cnt = t - base;
      if (cnt > 64) cnt = 64;
      int cnt4 = (cnt + 3) & ~3;
      for (int i = 0; i < cnt4; i += 4) {
        int r0 = __shfl(r, i), r1 = __shfl(r, i + 1);
        int r2 = __shfl(r, i + 2), r3 = __shfl(r, i + 3);
        float s0 = __shfl(sc, i), s1 = __shfl(sc, i + 1);
        float s2 = __shfl(sc, i + 2), s3 = __shfl(sc, i + 3);
        float2 v0 = *(const float2*)(x + (size_t)r0 * DIM + dbase);
        float2 v1 = *(const float2*)(x + (size_t)r1 * DIM + dbase);
        float2 v2 = *(const float2*)(x + (size_t)r2 * DIM + dbase);
        float2 v3 = *(const float2*)(x + (size_t)r3 * DIM + dbase);
        ax += s0 * v0.x; ay += s0 * v0.y;
        bx += s1 * v1.x; by += s1 * v1.y;
        cx += s2 * v2.x; cy += s2 * v2.y;
        dx += s3 * v3.x; dy += s3 * v3.y;
      }
    }
    float2 v0 = *(const float2*)(x0 + (size_t)n * DIM + dbase);
    float2 hv;
    hv.x = ((ax + bx) + (cx + dx)) + ALPHA * v0.x;
    hv.y = ((ay + by) + (cy + dy)) + ALPHA * v0.y;
    *(float2*)(h + (size_t)n * DIM + dbase) = hv;
  }
}

__global__ __launch_bounds__(256) void final_mfma(const float* __restrict__ W,
                                                  float* __restrict__ out, int N) {
  __shared__ short W_s[128][136];
  __shared__ short h_s[64][136];
  const int tid = threadIdx.x;
  const int lane = tid & 63;
  const int wave = tid >> 6;
  const int row0 = blockIdx.x * 64;

  for (int idx = tid; idx < 128 * 32; idx += 256) {
    int r = idx >> 5, c4 = idx & 31;
    float4 v = ((const float4*)(W + (size_t)r * DIM))[c4];
    *(short4*)&W_s[r][c4 * 4] = make_short4((short)f2bf(v.x), (short)f2bf(v.y),
                                            (short)f2bf(v.z), (short)f2bf(v.w));
  }
  for (int idx = tid; idx < 64 * 32; idx += 256) {
    int r = idx >> 5, c4 = idx & 31;
    int R = row0 + r;
    short4 sv = make_short4(0, 0, 0, 0);
    if (R < N) {
      float4 v = ((const float4*)(out + (size_t)R * DIM))[c4];
      sv = make_short4((short)f2bf(v.x), (short)f2bf(v.y), (short)f2bf(v.z),
                       (short)f2bf(v.w));
    }
    *(short4*)&h_s[r][c4 * 4] = sv;
  }
  __syncthreads();

  const int wr0 = wave * 16;
  const int arow = wr0 + (lane & 15);
  const int kg = (lane >> 4) * 8;
  short8v a[4];
#pragma unroll
  for (int s = 0; s < 4; ++s) a[s] = *(const short8v*)&h_s[arow][s * 32 + kg];

#pragma unroll
  for (int jt = 0; jt < 8; ++jt) {
    const int bcol = jt * 16 + (lane & 15);
    float4v acc = {0.0f, 0.0f, 0.0f, 0.0f};
#pragma unroll
    for (int s = 0; s < 4; ++s) {
      short8v b = *(const short8v*)&W_s[bcol][s * 32 + kg];
      acc = __builtin_amdgcn_mfma_f32_16x16x32_bf16(a[s], b, acc, 0, 0, 0);
    }
    const int rbase = row0 + wr0 + ((lane >> 4) << 2);
#pragma unroll
    for (int p = 0; p < 4; ++p) {
      int R = rbase + p;
      if (R < N) {
        size_t off = (size_t)R * DIM + jt * 16 + (lane & 15);
        out[off] = (1.0f - BETA) * out[off] + BETA * acc[p];
      }
    }
  }
}

// ---------------- last-resort atomic fallback ----------------
__global__ __launch_bounds__(256) void init_h(const float* __restrict__ x0,
                                              float* __restrict__ h, int total4) {
  int i = blockIdx.x * 256 + threadIdx.x;
  if (i < total4) {
    float4 v = ((const float4*)x0)[i];
    v.x *= ALPHA; v.y *= ALPHA; v.z *= ALPHA; v.w *= ALPHA;
    ((float4*)h)[i] = v;
  }
}

__global__ __launch_bounds__(256) void scatter_edges(const float* __restrict__ x,
                                                     const int* __restrict__ row,
                                                     const int* __restrict__ col,
                                                     const float* __restrict__ nrm,
                                                     float* __restrict__ h, int E) {
  int gid = blockIdx.x * 256 + threadIdx.x;
  int e = gid >> 5;
  if (e >= E) return;
  int d4 = (gid & 31) << 2;
  int r = row[e];
  int c = col[e];
  float s = (1.0f - ALPHA) * nrm[e];
  const float4 v = *(const float4*)(x + (size_t)r * DIM + d4);
  float* dst = h + (size_t)c * DIM + d4;
  atomicAdd(dst + 0, s * v.x);
  atomicAdd(dst + 1, s * v.y);
  atomicAdd(dst + 2, s * v.z);
  atomicAdd(dst + 3, s * v.w);
}

extern "C" void kernel_launch(void* const* d_in, const int* in_sizes, int n_in,
                              void* d_out, int out_size, void* d_ws, size_t ws_size,
                              hipStream_t stream) {
  const float* x = (const float*)d_in[0];
  const float* x0 = (const float*)d_in[1];
  const int* ei = (const int*)d_in[2];
  const float* nrm = (const float*)d_in[3];
  const float* W = (const float*)d_in[4];
  float* out = (float*)d_out;

  const int N = in_sizes[0] / DIM;
  const int E = in_sizes[2] / 2;
  const int* row = ei;
  const int* col = ei + E;

  // ws: counts[N+1] | offsets[N+1] | blockSums[256] | emeta int2[E] | xb bf16[N*DIM] | Wb bf16[128*128]
  const size_t csrNeed = (size_t)(2 * (N + 1) + 256) * sizeof(int) + (size_t)E * 8;
  const size_t fullNeed = csrNeed + (size_t)N * DIM * sizeof(short) + 128 * 128 * sizeof(short);

  if (ws_size >= csrNeed) {
    int* counts = (int*)d_ws;
    int* offsets = counts + (N + 1);
    int* blockSums = offsets + (N + 1);
    int2* emeta = (int2*)(blockSums + 256);
    short* xb = (short*)(emeta + E);
    short* Wb = xb + (size_t)N * DIM;

    const int eBlocks = (E + 255) / 256;
    const int nBlocks = (N + 255) / 256;
    const int n1Blocks = (N + 256) / 256;

    hipMemsetAsync(counts, 0, (size_t)(N + 1) * sizeof(int), stream);
    hipLaunchKernelGGL(count_edges, dim3(eBlocks), dim3(256), 0, stream, col, counts, E);
    hipLaunchKernelGGL(scan_blocks, dim3(nBlocks), dim3(256), 0, stream, counts, offsets, blockSums, N);
    hipLaunchKernelGGL(scan_sums, dim3(1), dim3(256), 0, stream, blockSums, nBlocks);
    hipLaunchKernelGGL(add_offsets, dim3(n1Blocks), dim3(256), 0, stream, offsets, blockSums, N, E);
    hipMemsetAsync(counts, 0, (size_t)(N + 1) * sizeof(int), stream);  // reuse as cursor
    hipLaunchKernelGGL(fill_edges, dim3(eBlocks), dim3(256), 0, stream, row, col, nrm, offsets,
                       counts, emeta, E);
    if (ws_size >= fullNeed) {
      int total4 = N * DIM / 4;
      hipLaunchKernelGGL(convert_x, dim3((total4 + 255) / 256), dim3(256), 0, stream, x, xb, total4);
      hipLaunchKernelGGL(convert_w, dim3(16), dim3(256), 0, stream, W, Wb);
      const int t16 = (N + 15) / 16;
      hipLaunchKernelGGL(gather_gemm, dim3(t16), dim3(256), 0, stream, (const unsigned*)xb, x0,
                         offsets, emeta, Wb, out, N);
    } else {
      const int gBlocks = (N + 3) / 4;
      hipLaunchKernelGGL(gather_nodes_f32, dim3(gBlocks), dim3(256), 0, stream, x, x0, offsets,
                         emeta, out, N);
      hipLaunchKernelGGL(final_mfma, dim3((N + 63) / 64), dim3(256), 0, stream, W, out, N);
    }
  } else {
    int total4 = N * DIM / 4;
    hipLaunchKernelGGL(init_h, dim3((total4 + 255) / 256), dim3(256), 0, stream, x0, out, total4);
    long long threads = (long long)E * 32;
    hipLaunchKernelGGL(scatter_edges, dim3((int)((threads + 255) / 256)), dim3(256), 0, stream, x,
                       row, col, nrm, out, E);
    hipLaunchKernelGGL(final_mfma, dim3((N + 63) / 64), dim3(256), 0, stream, W, out, N);
  }
}

// Round 11
// 125.663 us; speedup vs baseline: 9.9536x; 1.0567x over previous
//
#include <hip/hip_runtime.h>

#define DIM 128
#define ALPHA 0.1f
#define BETA 0.40546510810816438f  // log(0.5/1 + 1.0)

typedef __attribute__((ext_vector_type(8))) short short8v;  // 8 bf16 (4 VGPRs)
typedef __attribute__((ext_vector_type(4))) float float4v;  // MFMA acc

static __device__ inline unsigned short f2bf(float f) {
  union { float f; unsigned u; } a;
  a.f = f;
  unsigned r = a.u + 0x7fff + ((a.u >> 16) & 1);  // round-to-nearest-even
  return (unsigned short)(r >> 16);
}

// ---------------- fused prep: count_edges | convert_x | convert_w ----------------
// Independent jobs split by block range; count is atomic-bound, converts BW-bound.
__global__ __launch_bounds__(256) void prep(const int* __restrict__ col,
                                            int* __restrict__ counts,
                                            const float* __restrict__ x,
                                            short* __restrict__ xb,
                                            const float* __restrict__ W,
                                            short* __restrict__ Wb,
                                            int E, int total4, int cntBlocks,
                                            int cvtXBlocks) {
  int b = blockIdx.x;
  if (b < cntBlocks) {
    int e = b * 256 + threadIdx.x;
    if (e < E) atomicAdd(&counts[col[e]], 1);
  } else if (b < cntBlocks + cvtXBlocks) {
    int i = (b - cntBlocks) * 256 + threadIdx.x;
    if (i < total4) {
      float4 v = ((const float4*)x)[i];
      ((short4*)xb)[i] = make_short4((short)f2bf(v.x), (short)f2bf(v.y),
                                     (short)f2bf(v.z), (short)f2bf(v.w));
    }
  } else {
    int i = (b - cntBlocks - cvtXBlocks) * 256 + threadIdx.x;
    if (i < 128 * 32) {
      float4 v = ((const float4*)W)[i];
      ((short4*)Wb)[i] = make_short4((short)f2bf(v.x), (short)f2bf(v.y),
                                     (short)f2bf(v.z), (short)f2bf(v.w));
    }
  }
}

// per-block exclusive scan of counts -> offsets (local), block totals -> blockSums
__global__ __launch_bounds__(256) void scan_blocks(const int* __restrict__ counts,
                                                   int* __restrict__ offsets,
                                                   int* __restrict__ blockSums, int N) {
  __shared__ int sm[256];
  int tid = threadIdx.x;
  int gid = blockIdx.x * 256 + tid;
  int v = (gid < N) ? counts[gid] : 0;
  sm[tid] = v;
  __syncthreads();
  for (int off = 1; off < 256; off <<= 1) {
    int t = (tid >= off) ? sm[tid - off] : 0;
    __syncthreads();
    sm[tid] += t;
    __syncthreads();
  }
  if (gid < N) offsets[gid] = sm[tid] - v;
  if (tid == 255) blockSums[blockIdx.x] = sm[255];
}

// fused: each block redundantly scans blockSums (nb<=256) in LDS, adds its prefix,
// zeroes the fill cursor, and sets offsets[N]=E. Replaces scan_sums+add_offsets+memset.
__global__ __launch_bounds__(256) void scan_off(int* __restrict__ offsets,
                                                const int* __restrict__ blockSums,
                                                int* __restrict__ cursor,
                                                int N, int E, int nb) {
  __shared__ int sm[256];
  int tid = threadIdx.x;
  int v = (tid < nb) ? blockSums[tid] : 0;
  sm[tid] = v;
  __syncthreads();
  for (int off = 1; off < 256; off <<= 1) {
    int t = (tid >= off) ? sm[tid - off] : 0;
    __syncthreads();
    sm[tid] += t;
    __syncthreads();
  }
  int excl = sm[tid] - v;  // exclusive scan value at tid
  __syncthreads();
  sm[tid] = excl;
  __syncthreads();
  int pref = sm[blockIdx.x];  // exclusive prefix for this block's segment

  int gid = blockIdx.x * 256 + tid;
  if (gid < N) {
    offsets[gid] += pref;
    cursor[gid] = 0;
  } else if (gid == N) {
    offsets[N] = E;
  }
}

// packed (row, scale) per edge: one 8B store, one 8B load in gather
__global__ __launch_bounds__(256) void fill_edges(const int* __restrict__ row,
                                                  const int* __restrict__ col,
                                                  const float* __restrict__ nrm,
                                                  const int* __restrict__ offsets,
                                                  int* __restrict__ cursor,
                                                  int2* __restrict__ emeta, int E) {
  int e = blockIdx.x * 256 + threadIdx.x;
  if (e >= E) return;
  int c = col[e];
  int p = atomicAdd(&cursor[c], 1);
  int idx = offsets[c] + p;
  float s = (1.0f - ALPHA) * nrm[e];
  emeta[idx] = make_int2(row[e], __float_as_int(s));
}

// ---------------- fused gather + GEMM (proven round 10) ----------------
__global__ __launch_bounds__(256) void gather_gemm(const unsigned* __restrict__ xb,
                                                   const float* __restrict__ x0,
                                                   const int* __restrict__ offs,
                                                   const int2* __restrict__ emeta,
                                                   const short* __restrict__ Wb,
                                                   float* __restrict__ out, int N) {
  __shared__ unsigned short hb[16][136];
  const int tid = threadIdx.x;
  const int lane = tid & 63;
  const int wave = tid >> 6;
  const int row0 = blockIdx.x * 16;

  for (int q = 0; q < 4; ++q) {
    const int lr = wave * 4 + q;
    const int n = row0 + lr;
    unsigned packed = 0;
    if (n < N) {
      int s = offs[n], t = offs[n + 1];
      float accx[8], accy[8];
#pragma unroll
      for (int j = 0; j < 8; ++j) { accx[j] = 0.0f; accy[j] = 0.0f; }
      for (int base = s; base < t; base += 64) {
        int r = 0;
        float sc = 0.0f;
        if (base + lane < t) {
          int2 m = emeta[base + lane];
          r = m.x;
          sc = __int_as_float(m.y);
        }
        int cnt = t - base;
        if (cnt > 64) cnt = 64;
        int cnt8 = (cnt + 7) & ~7;
        for (int i = 0; i < cnt8; i += 8) {
#pragma unroll
          for (int j = 0; j < 8; ++j) {
            int rj = __shfl(r, i + j);
            float sj = __shfl(sc, i + j);
            unsigned u = xb[(size_t)rj * (DIM / 2) + lane];
            accx[j] += sj * __uint_as_float(u << 16);
            accy[j] += sj * __uint_as_float(u & 0xffff0000u);
          }
        }
      }
      float sx = ((accx[0] + accx[1]) + (accx[2] + accx[3])) +
                 ((accx[4] + accx[5]) + (accx[6] + accx[7]));
      float sy = ((accy[0] + accy[1]) + (accy[2] + accy[3])) +
                 ((accy[4] + accy[5]) + (accy[6] + accy[7]));
      float2 v0 = *(const float2*)(x0 + (size_t)n * DIM + 2 * lane);
      float hx = sx + ALPHA * v0.x;
      float hy = sy + ALPHA * v0.y;
      packed = (unsigned)f2bf(hx) | ((unsigned)f2bf(hy) << 16);
    }
    *(unsigned*)&hb[lr][2 * lane] = packed;
  }
  __syncthreads();

  const int arow = lane & 15;
  const int kg = (lane >> 4) * 8;
  short8v a[4];
#pragma unroll
  for (int s = 0; s < 4; ++s) a[s] = *(const short8v*)&hb[arow][s * 32 + kg];

#pragma unroll
  for (int j2 = 0; j2 < 2; ++j2) {
    const int jt = wave * 2 + j2;
    const int bcol = jt * 16 + (lane & 15);
    float4v acc = {0.0f, 0.0f, 0.0f, 0.0f};
#pragma unroll
    for (int s = 0; s < 4; ++s) {
      short8v b = *(const short8v*)(Wb + (size_t)bcol * DIM + s * 32 + kg);
      acc = __builtin_amdgcn_mfma_f32_16x16x32_bf16(a[s], b, acc, 0, 0, 0);
    }
    const int lr0 = (lane >> 4) << 2;
#pragma unroll
    for (int p = 0; p < 4; ++p) {
      int R = row0 + lr0 + p;
      if (R < N) {
        int c = jt * 16 + (lane & 15);
        float hv = __uint_as_float(((unsigned)hb[lr0 + p][c]) << 16);
        out[(size_t)R * DIM + c] = (1.0f - BETA) * hv + BETA * acc[p];
      }
    }
  }
}

// ---------------- mid-tier: unfused f32 gather + LDS-staged MFMA ----------------
__global__ __launch_bounds__(256) void count_edges(const int* __restrict__ col,
                                                   int* __restrict__ counts, int E) {
  int e = blockIdx.x * 256 + threadIdx.x;
  if (e < E) atomicAdd(&counts[col[e]], 1);
}

__global__ __launch_bounds__(256) void gather_nodes_f32(const float* __restrict__ x,
                                                        const float* __restrict__ x0,
                                                        const int* __restrict__ offs,
                                                        const int2* __restrict__ emeta,
                                                        float* __restrict__ h, int N) {
  int lane = threadIdx.x & 63;
  int gwave = blockIdx.x * 4 + (threadIdx.x >> 6);
  int nwaves = gridDim.x * 4;
  int dbase = 2 * lane;
  for (int n = gwave; n < N; n += nwaves) {
    int s = offs[n], t = offs[n + 1];
    float ax = 0, ay = 0, bx = 0, by = 0, cx = 0, cy = 0, dx = 0, dy = 0;
    for (int base = s; base < t; base += 64) {
      int r = 0;
      float sc = 0.0f;
      if (base + lane < t) {
        int2 m = emeta[base + lane];
        r = m.x;
        sc = __int_as_float(m.y);
      }
      int cnt = t - base;
      if (cnt > 64) cnt = 64;
      int cnt4 = (cnt + 3) & ~3;
      for (int i = 0; i < cnt4; i += 4) {
        int r0 = __shfl(r, i), r1 = __shfl(r, i + 1);
        int r2 = __shfl(r, i + 2), r3 = __shfl(r, i + 3);
        float s0 = __shfl(sc, i), s1 = __shfl(sc, i + 1);
        float s2 = __shfl(sc, i + 2), s3 = __shfl(sc, i + 3);
        float2 v0 = *(const float2*)(x + (size_t)r0 * DIM + dbase);
        float2 v1 = *(const float2*)(x + (size_t)r1 * DIM + dbase);
        float2 v2 = *(const float2*)(x + (size_t)r2 * DIM + dbase);
        float2 v3 = *(const float2*)(x + (size_t)r3 * DIM + dbase);
        ax += s0 * v0.x; ay += s0 * v0.y;
        bx += s1 * v1.x; by += s1 * v1.y;
        cx += s2 * v2.x; cy += s2 * v2.y;
        dx += s3 * v3.x; dy += s3 * v3.y;
      }
    }
    float2 v0 = *(const float2*)(x0 + (size_t)n * DIM + dbase);
    float2 hv;
    hv.x = ((ax + bx) + (cx + dx)) + ALPHA * v0.x;
    hv.y = ((ay + by) + (cy + dy)) + ALPHA * v0.y;
    *(float2*)(h + (size_t)n * DIM + dbase) = hv;
  }
}

__global__ __launch_bounds__(256) void final_mfma(const float* __restrict__ W,
                                                  float* __restrict__ out, int N) {
  __shared__ short W_s[128][136];
  __shared__ short h_s[64][136];
  const int tid = threadIdx.x;
  const int lane = tid & 63;
  const int wave = tid >> 6;
  const int row0 = blockIdx.x * 64;

  for (int idx = tid; idx < 128 * 32; idx += 256) {
    int r = idx >> 5, c4 = idx & 31;
    float4 v = ((const float4*)(W + (size_t)r * DIM))[c4];
    *(short4*)&W_s[r][c4 * 4] = make_short4((short)f2bf(v.x), (short)f2bf(v.y),
                                            (short)f2bf(v.z), (short)f2bf(v.w));
  }
  for (int idx = tid; idx < 64 * 32; idx += 256) {
    int r = idx >> 5, c4 = idx & 31;
    int R = row0 + r;
    short4 sv = make_short4(0, 0, 0, 0);
    if (R < N) {
      float4 v = ((const float4*)(out + (size_t)R * DIM))[c4];
      sv = make_short4((short)f2bf(v.x), (short)f2bf(v.y), (short)f2bf(v.z),
                       (short)f2bf(v.w));
    }
    *(short4*)&h_s[r][c4 * 4] = sv;
  }
  __syncthreads();

  const int wr0 = wave * 16;
  const int arow = wr0 + (lane & 15);
  const int kg = (lane >> 4) * 8;
  short8v a[4];
#pragma unroll
  for (int s = 0; s < 4; ++s) a[s] = *(const short8v*)&h_s[arow][s * 32 + kg];

#pragma unroll
  for (int jt = 0; jt < 8; ++jt) {
    const int bcol = jt * 16 + (lane & 15);
    float4v acc = {0.0f, 0.0f, 0.0f, 0.0f};
#pragma unroll
    for (int s = 0; s < 4; ++s) {
      short8v b = *(const short8v*)&W_s[bcol][s * 32 + kg];
      acc = __builtin_amdgcn_mfma_f32_16x16x32_bf16(a[s], b, acc, 0, 0, 0);
    }
    const int rbase = row0 + wr0 + ((lane >> 4) << 2);
#pragma unroll
    for (int p = 0; p < 4; ++p) {
      int R = rbase + p;
      if (R < N) {
        size_t off = (size_t)R * DIM + jt * 16 + (lane & 15);
        out[off] = (1.0f - BETA) * out[off] + BETA * acc[p];
      }
    }
  }
}

// ---------------- last-resort atomic fallback ----------------
__global__ __launch_bounds__(256) void init_h(const float* __restrict__ x0,
                                              float* __restrict__ h, int total4) {
  int i = blockIdx.x * 256 + threadIdx.x;
  if (i < total4) {
    float4 v = ((const float4*)x0)[i];
    v.x *= ALPHA; v.y *= ALPHA; v.z *= ALPHA; v.w *= ALPHA;
    ((float4*)h)[i] = v;
  }
}

__global__ __launch_bounds__(256) void scatter_edges(const float* __restrict__ x,
                                                     const int* __restrict__ row,
                                                     const int* __restrict__ col,
                                                     const float* __restrict__ nrm,
                                                     float* __restrict__ h, int E) {
  int gid = blockIdx.x * 256 + threadIdx.x;
  int e = gid >> 5;
  if (e >= E) return;
  int d4 = (gid & 31) << 2;
  int r = row[e];
  int c = col[e];
  float s = (1.0f - ALPHA) * nrm[e];
  const float4 v = *(const float4*)(x + (size_t)r * DIM + d4);
  float* dst = h + (size_t)c * DIM + d4;
  atomicAdd(dst + 0, s * v.x);
  atomicAdd(dst + 1, s * v.y);
  atomicAdd(dst + 2, s * v.z);
  atomicAdd(dst + 3, s * v.w);
}

extern "C" void kernel_launch(void* const* d_in, const int* in_sizes, int n_in,
                              void* d_out, int out_size, void* d_ws, size_t ws_size,
                              hipStream_t stream) {
  const float* x = (const float*)d_in[0];
  const float* x0 = (const float*)d_in[1];
  const int* ei = (const int*)d_in[2];
  const float* nrm = (const float*)d_in[3];
  const float* W = (const float*)d_in[4];
  float* out = (float*)d_out;

  const int N = in_sizes[0] / DIM;
  const int E = in_sizes[2] / 2;
  const int* row = ei;
  const int* col = ei + E;

  // ws: counts[N+1] | offsets[N+1] | blockSums[256] | cursor[N] | emeta int2[E]
  //     | xb bf16[N*DIM] | Wb bf16[128*128]
  const size_t csrNeed =
      (size_t)(2 * (N + 1) + 256 + N) * sizeof(int) + (size_t)E * 8;
  const size_t fullNeed =
      csrNeed + (size_t)N * DIM * sizeof(short) + 128 * 128 * sizeof(short);

  const int eBlocks = (E + 255) / 256;
  const int nBlocks = (N + 255) / 256;       // scan segments over counts
  const int n1Blocks = (N + 256) / 256;      // covers N+1 entries

  if (ws_size >= csrNeed && nBlocks <= 256) {
    int* counts = (int*)d_ws;
    int* offsets = counts + (N + 1);
    int* blockSums = offsets + (N + 1);
    int* cursor = blockSums + 256;
    int2* emeta = (int2*)(cursor + N);
    short* xb = (short*)(emeta + E);
    short* Wb = xb + (size_t)N * DIM;

    hipMemsetAsync(counts, 0, (size_t)(N + 1) * sizeof(int), stream);

    if (ws_size >= fullNeed) {
      const int total4 = N * DIM / 4;
      const int cvtXBlocks = (total4 + 255) / 256;
      const int prepBlocks = eBlocks + cvtXBlocks + 16;
      hipLaunchKernelGGL(prep, dim3(prepBlocks), dim3(256), 0, stream, col, counts, x, xb, W, Wb,
                         E, total4, eBlocks, cvtXBlocks);
      hipLaunchKernelGGL(scan_blocks, dim3(nBlocks), dim3(256), 0, stream, counts, offsets,
                         blockSums, N);
      hipLaunchKernelGGL(scan_off, dim3(n1Blocks), dim3(256), 0, stream, offsets, blockSums,
                         cursor, N, E, nBlocks);
      hipLaunchKernelGGL(fill_edges, dim3(eBlocks), dim3(256), 0, stream, row, col, nrm, offsets,
                         cursor, emeta, E);
      const int t16 = (N + 15) / 16;
      hipLaunchKernelGGL(gather_gemm, dim3(t16), dim3(256), 0, stream, (const unsigned*)xb, x0,
                         offsets, emeta, Wb, out, N);
    } else {
      hipLaunchKernelGGL(count_edges, dim3(eBlocks), dim3(256), 0, stream, col, counts, E);
      hipLaunchKernelGGL(scan_blocks, dim3(nBlocks), dim3(256), 0, stream, counts, offsets,
                         blockSums, N);
      hipLaunchKernelGGL(scan_off, dim3(n1Blocks), dim3(256), 0, stream, offsets, blockSums,
                         cursor, N, E, nBlocks);
      hipLaunchKernelGGL(fill_edges, dim3(eBlocks), dim3(256), 0, stream, row, col, nrm, offsets,
                         cursor, emeta, E);
      const int gBlocks = (N + 3) / 4;
      hipLaunchKernelGGL(gather_nodes_f32, dim3(gBlocks), dim3(256), 0, stream, x, x0, offsets,
                         emeta, out, N);
      hipLaunchKernelGGL(final_mfma, dim3((N + 63) / 64), dim3(256), 0, stream, W, out, N);
    }
  } else {
    int total4 = N * DIM / 4;
    hipLaunchKernelGGL(init_h, dim3((total4 + 255) / 256), dim3(256), 0, stream, x0, out, total4);
    long long threads = (long long)E * 32;
    hipLaunchKernelGGL(scatter_edges, dim3((int)((threads + 255) / 256)), dim3(256), 0, stream, x,
                       row, col, nrm, out, E);
    hipLaunchKernelGGL(final_mfma, dim3((N + 63) / 64), dim3(256), 0, stream, W, out, N);
  }
}

// Round 14
// 119.355 us; speedup vs baseline: 10.4797x; 1.0529x over previous
//
#include <hip/hip_runtime.h>

#define DIM 128
#define ALPHA 0.1f
#define BETA 0.40546510810816438f  // log(0.5/1 + 1.0)

typedef __attribute__((ext_vector_type(8))) short short8v;  // 8 bf16 (4 VGPRs)
typedef __attribute__((ext_vector_type(4))) float float4v;  // MFMA acc

static __device__ inline unsigned short f2bf(float f) {
  union { float f; unsigned u; } a;
  a.f = f;
  unsigned r = a.u + 0x7fff + ((a.u >> 16) & 1);  // round-to-nearest-even
  return (unsigned short)(r >> 16);
}

// ---------------- fused prep: count+rank | convert_x | convert_w ----------------
// count section stores each edge's rank within its destination node (the atomicAdd
// return value) -> fill needs no atomics at all.
__global__ __launch_bounds__(256) void prep(const int* __restrict__ col,
                                            int* __restrict__ counts,
                                            int* __restrict__ rank,
                                            const float* __restrict__ x,
                                            short* __restrict__ xb,
                                            const float* __restrict__ W,
                                            short* __restrict__ Wb,
                                            int E, int total4, int cntBlocks,
                                            int cvtXBlocks) {
  int b = blockIdx.x;
  if (b < cntBlocks) {
    int e = b * 256 + threadIdx.x;
    if (e < E) rank[e] = atomicAdd(&counts[col[e]], 1);
  } else if (b < cntBlocks + cvtXBlocks) {
    int i = (b - cntBlocks) * 256 + threadIdx.x;
    if (i < total4) {
      float4 v = ((const float4*)x)[i];
      ((short4*)xb)[i] = make_short4((short)f2bf(v.x), (short)f2bf(v.y),
                                     (short)f2bf(v.z), (short)f2bf(v.w));
    }
  } else {
    int i = (b - cntBlocks - cvtXBlocks) * 256 + threadIdx.x;
    if (i < 128 * 32) {
      float4 v = ((const float4*)W)[i];
      ((short4*)Wb)[i] = make_short4((short)f2bf(v.x), (short)f2bf(v.y),
                                     (short)f2bf(v.z), (short)f2bf(v.w));
    }
  }
}

// per-block exclusive scan of counts -> offsets (local), block totals -> blockSums
__global__ __launch_bounds__(256) void scan_blocks(const int* __restrict__ counts,
                                                   int* __restrict__ offsets,
                                                   int* __restrict__ blockSums, int N) {
  __shared__ int sm[256];
  int tid = threadIdx.x;
  int gid = blockIdx.x * 256 + tid;
  int v = (gid < N) ? counts[gid] : 0;
  sm[tid] = v;
  __syncthreads();
  for (int off = 1; off < 256; off <<= 1) {
    int t = (tid >= off) ? sm[tid - off] : 0;
    __syncthreads();
    sm[tid] += t;
    __syncthreads();
  }
  if (gid < N) offsets[gid] = sm[tid] - v;
  if (tid == 255) blockSums[blockIdx.x] = sm[255];
}

// each block redundantly scans blockSums (nb<=256) in LDS, adds its prefix,
// sets offsets[N]=E. (cursor gone: fill is atomic-free now)
__global__ __launch_bounds__(256) void scan_off(int* __restrict__ offsets,
                                                const int* __restrict__ blockSums,
                                                int N, int E, int nb) {
  __shared__ int sm[256];
  int tid = threadIdx.x;
  int v = (tid < nb) ? blockSums[tid] : 0;
  sm[tid] = v;
  __syncthreads();
  for (int off = 1; off < 256; off <<= 1) {
    int t = (tid >= off) ? sm[tid - off] : 0;
    __syncthreads();
    sm[tid] += t;
    __syncthreads();
  }
  int excl = sm[tid] - v;
  __syncthreads();
  sm[tid] = excl;
  __syncthreads();
  int pref = sm[blockIdx.x];

  int gid = blockIdx.x * 256 + tid;
  if (gid < N) offsets[gid] += pref;
  else if (gid == N) offsets[N] = E;
}

// atomic-free fill: slot = offsets[col] + rank (precomputed in prep)
__global__ __launch_bounds__(256) void fill_edges(const int* __restrict__ row,
                                                  const int* __restrict__ col,
                                                  const float* __restrict__ nrm,
                                                  const int* __restrict__ offsets,
                                                  const int* __restrict__ rank,
                                                  int2* __restrict__ emeta, int E) {
  int e = blockIdx.x * 256 + threadIdx.x;
  if (e >= E) return;
  int c = col[e];
  int idx = offsets[c] + rank[e];
  float s = (1.0f - ALPHA) * nrm[e];
  emeta[idx] = make_int2(row[e], __float_as_int(s));
}

// ---------------- fused gather + GEMM ----------------
// Phase 1: wave gathers 4 nodes; edge meta read via wave-uniform broadcast loads
// (sequential addresses -> L1-resident) instead of shfl/ds_bpermute chains.
// Phase 2: 16x128 @ 128x128^T bf16 MFMA from LDS tile + L2-resident global Wb.
__global__ __launch_bounds__(256) void gather_gemm(const unsigned* __restrict__ xb,
                                                   const float* __restrict__ x0,
                                                   const int* __restrict__ offs,
                                                   const int2* __restrict__ emeta,
                                                   const short* __restrict__ Wb,
                                                   float* __restrict__ out, int N) {
  __shared__ unsigned short hb[16][136];
  const int tid = threadIdx.x;
  const int lane = tid & 63;
  const int wave = tid >> 6;
  const int row0 = blockIdx.x * 16;

  for (int q = 0; q < 4; ++q) {
    const int lr = wave * 4 + q;
    const int n = row0 + lr;
    unsigned packed = 0;
    if (n < N) {
      const int s = offs[n], t = offs[n + 1];
      float2 v0 = *(const float2*)(x0 + (size_t)n * DIM + 2 * lane);  // in flight early
      float accx[8], accy[8];
#pragma unroll
      for (int j = 0; j < 8; ++j) { accx[j] = 0.0f; accy[j] = 0.0f; }
      int i = s;
      for (; i + 8 <= t; i += 8) {
#pragma unroll
        for (int j = 0; j < 8; ++j) {
          int2 m = emeta[i + j];
          float sj = __int_as_float(m.y);
          unsigned u = xb[(size_t)m.x * (DIM / 2) + lane];
          accx[j] += sj * __uint_as_float(u << 16);
          accy[j] += sj * __uint_as_float(u & 0xffff0000u);
        }
      }
      for (; i < t; ++i) {  // wave-uniform remainder (<8)
        int2 m = emeta[i];
        float sj = __int_as_float(m.y);
        unsigned u = xb[(size_t)m.x * (DIM / 2) + lane];
        accx[0] += sj * __uint_as_float(u << 16);
        accy[0] += sj * __uint_as_float(u & 0xffff0000u);
      }
      float sx = ((accx[0] + accx[1]) + (accx[2] + accx[3])) +
                 ((accx[4] + accx[5]) + (accx[6] + accx[7]));
      float sy = ((accy[0] + accy[1]) + (accy[2] + accy[3])) +
                 ((accy[4] + accy[5]) + (accy[6] + accy[7]));
      float hx = sx + ALPHA * v0.x;
      float hy = sy + ALPHA * v0.y;
      packed = (unsigned)f2bf(hx) | ((unsigned)f2bf(hy) << 16);
    }
    *(unsigned*)&hb[lr][2 * lane] = packed;
  }
  __syncthreads();

  const int arow = lane & 15;
  const int kg = (lane >> 4) * 8;
  short8v a[4];
#pragma unroll
  for (int s = 0; s < 4; ++s) a[s] = *(const short8v*)&hb[arow][s * 32 + kg];

#pragma unroll
  for (int j2 = 0; j2 < 2; ++j2) {
    const int jt = wave * 2 + j2;
    const int bcol = jt * 16 + (lane & 15);
    float4v acc = {0.0f, 0.0f, 0.0f, 0.0f};
#pragma unroll
    for (int s = 0; s < 4; ++s) {
      short8v b = *(const short8v*)(Wb + (size_t)bcol * DIM + s * 32 + kg);
      acc = __builtin_amdgcn_mfma_f32_16x16x32_bf16(a[s], b, acc, 0, 0, 0);
    }
    const int lr0 = (lane >> 4) << 2;
#pragma unroll
    for (int p = 0; p < 4; ++p) {
      int R = row0 + lr0 + p;
      if (R < N) {
        int c = jt * 16 + (lane & 15);
        float hv = __uint_as_float(((unsigned)hb[lr0 + p][c]) << 16);
        out[(size_t)R * DIM + c] = (1.0f - BETA) * hv + BETA * acc[p];
      }
    }
  }
}

// ---------------- mid-tier: count+rank, f32 gather + LDS-staged MFMA ----------------
__global__ __launch_bounds__(256) void count_edges(const int* __restrict__ col,
                                                   int* __restrict__ counts,
                                                   int* __restrict__ rank, int E) {
  int e = blockIdx.x * 256 + threadIdx.x;
  if (e < E) rank[e] = atomicAdd(&counts[col[e]], 1);
}

__global__ __launch_bounds__(256) void gather_nodes_f32(const float* __restrict__ x,
                                                        const float* __restrict__ x0,
                                                        const int* __restrict__ offs,
                                                        const int2* __restrict__ emeta,
                                                        float* __restrict__ h, int N) {
  int lane = threadIdx.x & 63;
  int gwave = blockIdx.x * 4 + (threadIdx.x >> 6);
  int nwaves = gridDim.x * 4;
  int dbase = 2 * lane;
  for (int n = gwave; n < N; n += nwaves) {
    int s = offs[n], t = offs[n + 1];
    float ax = 0, ay = 0, bx = 0, by = 0;
    int i = s;
    for (; i + 4 <= t; i += 4) {
      int2 m0 = emeta[i], m1 = emeta[i + 1], m2 = emeta[i + 2], m3 = emeta[i + 3];
      float2 v0 = *(const float2*)(x + (size_t)m0.x * DIM + dbase);
      float2 v1 = *(const float2*)(x + (size_t)m1.x * DIM + dbase);
      float2 v2 = *(const float2*)(x + (size_t)m2.x * DIM + dbase);
      float2 v3 = *(const float2*)(x + (size_t)m3.x * DIM + dbase);
      ax += __int_as_float(m0.y) * v0.x; ay += __int_as_float(m0.y) * v0.y;
      bx += __int_as_float(m1.y) * v1.x; by += __int_as_float(m1.y) * v1.y;
      ax += __int_as_float(m2.y) * v2.x; ay += __int_as_float(m2.y) * v2.y;
      bx += __int_as_float(m3.y) * v3.x; by += __int_as_float(m3.y) * v3.y;
    }
    for (; i < t; ++i) {
      int2 m = emeta[i];
      float2 v = *(const float2*)(x + (size_t)m.x * DIM + dbase);
      ax += __int_as_float(m.y) * v.x; ay += __int_as_float(m.y) * v.y;
    }
    float2 v0 = *(const float2*)(x0 + (size_t)n * DIM + dbase);
    float2 hv;
    hv.x = (ax + bx) + ALPHA * v0.x;
    hv.y = (ay + by) + ALPHA * v0.y;
    *(float2*)(h + (size_t)n * DIM + dbase) = hv;
  }
}

__global__ __launch_bounds__(256) void final_mfma(const float* __restrict__ W,
                                                  float* __restrict__ out, int N) {
  __shared__ short W_s[128][136];
  __shared__ short h_s[64][136];
  const int tid = threadIdx.x;
  const int lane = tid & 63;
  const int wave = tid >> 6;
  const int row0 = blockIdx.x * 64;

  for (int idx = tid; idx < 128 * 32; idx += 256) {
    int r = idx >> 5, c4 = idx & 31;
    float4 v = ((const float4*)(W + (size_t)r * DIM))[c4];
    *(short4*)&W_s[r][c4 * 4] = make_short4((short)f2bf(v.x), (short)f2bf(v.y),
                                            (short)f2bf(v.z), (short)f2bf(v.w));
  }
  for (int idx = tid; idx < 64 * 32; idx += 256) {
    int r = idx >> 5, c4 = idx & 31;
    int R = row0 + r;
    short4 sv = make_short4(0, 0, 0, 0);
    if (R < N) {
      float4 v = ((const float4*)(out + (size_t)R * DIM))[c4];
      sv = make_short4((short)f2bf(v.x), (short)f2bf(v.y), (short)f2bf(v.z),
                       (short)f2bf(v.w));
    }
    *(short4*)&h_s[r][c4 * 4] = sv;
  }
  __syncthreads();

  const int wr0 = wave * 16;
  const int arow = wr0 + (lane & 15);
  const int kg = (lane >> 4) * 8;
  short8v a[4];
#pragma unroll
  for (int s = 0; s < 4; ++s) a[s] = *(const short8v*)&h_s[arow][s * 32 + kg];

#pragma unroll
  for (int jt = 0; jt < 8; ++jt) {
    const int bcol = jt * 16 + (lane & 15);
    float4v acc = {0.0f, 0.0f, 0.0f, 0.0f};
#pragma unroll
    for (int s = 0; s < 4; ++s) {
      short8v b = *(const short8v*)&W_s[bcol][s * 32 + kg];
      acc = __builtin_amdgcn_mfma_f32_16x16x32_bf16(a[s], b, acc, 0, 0, 0);
    }
    const int rbase = row0 + wr0 + ((lane >> 4) << 2);
#pragma unroll
    for (int p = 0; p < 4; ++p) {
      int R = rbase + p;
      if (R < N) {
        size_t off = (size_t)R * DIM + jt * 16 + (lane & 15);
        out[off] = (1.0f - BETA) * out[off] + BETA * acc[p];
      }
    }
  }
}

// ---------------- last-resort atomic fallback ----------------
__global__ __launch_bounds__(256) void init_h(const float* __restrict__ x0,
                                              float* __restrict__ h, int total4) {
  int i = blockIdx.x * 256 + threadIdx.x;
  if (i < total4) {
    float4 v = ((const float4*)x0)[i];
    v.x *= ALPHA; v.y *= ALPHA; v.z *= ALPHA; v.w *= ALPHA;
    ((float4*)h)[i] = v;
  }
}

__global__ __launch_bounds__(256) void scatter_edges(const float* __restrict__ x,
                                                     const int* __restrict__ row,
                                                     const int* __restrict__ col,
                                                     const float* __restrict__ nrm,
                                                     float* __restrict__ h, int E) {
  int gid = blockIdx.x * 256 + threadIdx.x;
  int e = gid >> 5;
  if (e >= E) return;
  int d4 = (gid & 31) << 2;
  int r = row[e];
  int c = col[e];
  float s = (1.0f - ALPHA) * nrm[e];
  const float4 v = *(const float4*)(x + (size_t)r * DIM + d4);
  float* dst = h + (size_t)c * DIM + d4;
  atomicAdd(dst + 0, s * v.x);
  atomicAdd(dst + 1, s * v.y);
  atomicAdd(dst + 2, s * v.z);
  atomicAdd(dst + 3, s * v.w);
}

extern "C" void kernel_launch(void* const* d_in, const int* in_sizes, int n_in,
                              void* d_out, int out_size, void* d_ws, size_t ws_size,
                              hipStream_t stream) {
  const float* x = (const float*)d_in[0];
  const float* x0 = (const float*)d_in[1];
  const int* ei = (const int*)d_in[2];
  const float* nrm = (const float*)d_in[3];
  const float* W = (const float*)d_in[4];
  float* out = (float*)d_out;

  const int N = in_sizes[0] / DIM;
  const int E = in_sizes[2] / 2;
  const int* row = ei;
  const int* col = ei + E;

  // ws: counts[N+1] | offsets[N+1] | blockSums[256] | rank[E] | emeta int2[E]
  //     | xb bf16[N*DIM] | Wb bf16[128*128]
  const size_t csrNeed =
      (size_t)(2 * (N + 1) + 256 + E) * sizeof(int) + (size_t)E * 8;
  const size_t fullNeed =
      csrNeed + (size_t)N * DIM * sizeof(short) + 128 * 128 * sizeof(short);

  const int eBlocks = (E + 255) / 256;
  const int nBlocks = (N + 255) / 256;
  const int n1Blocks = (N + 256) / 256;

  if (ws_size >= csrNeed && nBlocks <= 256) {
    int* counts = (int*)d_ws;
    int* offsets = counts + (N + 1);
    int* blockSums = offsets + (N + 1);
    int* rank = blockSums + 256;
    int2* emeta = (int2*)(rank + E);
    short* xb = (short*)(emeta + E);
    short* Wb = xb + (size_t)N * DIM;

    hipMemsetAsync(counts, 0, (size_t)(N + 1) * sizeof(int), stream);

    if (ws_size >= fullNeed) {
      const int total4 = N * DIM / 4;
      const int cvtXBlocks = (total4 + 255) / 256;
      const int prepBlocks = eBlocks + cvtXBlocks + 16;
      hipLaunchKernelGGL(prep, dim3(prepBlocks), dim3(256), 0, stream, col, counts, rank, x, xb,
                         W, Wb, E, total4, eBlocks, cvtXBlocks);
      hipLaunchKernelGGL(scan_blocks, dim3(nBlocks), dim3(256), 0, stream, counts, offsets,
                         blockSums, N);
      hipLaunchKernelGGL(scan_off, dim3(n1Blocks), dim3(256), 0, stream, offsets, blockSums, N, E,
                         nBlocks);
      hipLaunchKernelGGL(fill_edges, dim3(eBlocks), dim3(256), 0, stream, row, col, nrm, offsets,
                         rank, emeta, E);
      const int t16 = (N + 15) / 16;
      hipLaunchKernelGGL(gather_gemm, dim3(t16), dim3(256), 0, stream, (const unsigned*)xb, x0,
                         offsets, emeta, Wb, out, N);
    } else {
      hipLaunchKernelGGL(count_edges, dim3(eBlocks), dim3(256), 0, stream, col, counts, rank, E);
      hipLaunchKernelGGL(scan_blocks, dim3(nBlocks), dim3(256), 0, stream, counts, offsets,
                         blockSums, N);
      hipLaunchKernelGGL(scan_off, dim3(n1Blocks), dim3(256), 0, stream, offsets, blockSums, N, E,
                         nBlocks);
      hipLaunchKernelGGL(fill_edges, dim3(eBlocks), dim3(256), 0, stream, row, col, nrm, offsets,
                         rank, emeta, E);
      const int gBlocks = (N + 3) / 4;
      hipLaunchKernelGGL(gather_nodes_f32, dim3(gBlocks), dim3(256), 0, stream, x, x0, offsets,
                         emeta, out, N);
      hipLaunchKernelGGL(final_mfma, dim3((N + 63) / 64), dim3(256), 0, stream, W, out, N);
    }
  } else {
    int total4 = N * DIM / 4;
    hipLaunchKernelGGL(init_h, dim3((total4 + 255) / 256), dim3(256), 0, stream, x0, out, total4);
    long long threads = (long long)E * 32;
    hipLaunchKernelGGL(scatter_edges, dim3((int)((threads + 255) / 256)), dim3(256), 0, stream, x,
                       row, col, nrm, out, E);
    hipLaunchKernelGGL(final_mfma, dim3((N + 63) / 64), dim3(256), 0, stream, W, out, N);
  }
}

// Round 15
// 102.390 us; speedup vs baseline: 12.2161x; 1.1657x over previous
//
#include <hip/hip_runtime.h>

#define DIM 128
#define ALPHA 0.1f
#define BETA 0.40546510810816438f  // log(0.5/1 + 1.0)

typedef __attribute__((ext_vector_type(8))) short short8v;  // 8 bf16 (4 VGPRs)
typedef __attribute__((ext_vector_type(4))) float float4v;  // MFMA acc

static __device__ inline unsigned short f2bf(float f) {
  union { float f; unsigned u; } a;
  a.f = f;
  unsigned r = a.u + 0x7fff + ((a.u >> 16) & 1);  // round-to-nearest-even
  return (unsigned short)(r >> 16);
}

// ---------------- fused prep: count+rank | convert_x | convert_w ----------------
// count section stores each edge's rank within its destination node (the atomicAdd
// return value) -> fill needs no atomics at all. (R14: won ~23us vs atomic fill)
__global__ __launch_bounds__(256) void prep(const int* __restrict__ col,
                                            int* __restrict__ counts,
                                            int* __restrict__ rank,
                                            const float* __restrict__ x,
                                            short* __restrict__ xb,
                                            const float* __restrict__ W,
                                            short* __restrict__ Wb,
                                            int E, int total4, int cntBlocks,
                                            int cvtXBlocks) {
  int b = blockIdx.x;
  if (b < cntBlocks) {
    int e = b * 256 + threadIdx.x;
    if (e < E) rank[e] = atomicAdd(&counts[col[e]], 1);
  } else if (b < cntBlocks + cvtXBlocks) {
    int i = (b - cntBlocks) * 256 + threadIdx.x;
    if (i < total4) {
      float4 v = ((const float4*)x)[i];
      ((short4*)xb)[i] = make_short4((short)f2bf(v.x), (short)f2bf(v.y),
                                     (short)f2bf(v.z), (short)f2bf(v.w));
    }
  } else {
    int i = (b - cntBlocks - cvtXBlocks) * 256 + threadIdx.x;
    if (i < 128 * 32) {
      float4 v = ((const float4*)W)[i];
      ((short4*)Wb)[i] = make_short4((short)f2bf(v.x), (short)f2bf(v.y),
                                     (short)f2bf(v.z), (short)f2bf(v.w));
    }
  }
}

// per-block exclusive scan of counts -> offsets (local), block totals -> blockSums
__global__ __launch_bounds__(256) void scan_blocks(const int* __restrict__ counts,
                                                   int* __restrict__ offsets,
                                                   int* __restrict__ blockSums, int N) {
  __shared__ int sm[256];
  int tid = threadIdx.x;
  int gid = blockIdx.x * 256 + tid;
  int v = (gid < N) ? counts[gid] : 0;
  sm[tid] = v;
  __syncthreads();
  for (int off = 1; off < 256; off <<= 1) {
    int t = (tid >= off) ? sm[tid - off] : 0;
    __syncthreads();
    sm[tid] += t;
    __syncthreads();
  }
  if (gid < N) offsets[gid] = sm[tid] - v;
  if (tid == 255) blockSums[blockIdx.x] = sm[255];
}

// each block redundantly scans blockSums (nb<=256) in LDS, adds its prefix,
// sets offsets[N]=E.
__global__ __launch_bounds__(256) void scan_off(int* __restrict__ offsets,
                                                const int* __restrict__ blockSums,
                                                int N, int E, int nb) {
  __shared__ int sm[256];
  int tid = threadIdx.x;
  int v = (tid < nb) ? blockSums[tid] : 0;
  sm[tid] = v;
  __syncthreads();
  for (int off = 1; off < 256; off <<= 1) {
    int t = (tid >= off) ? sm[tid - off] : 0;
    __syncthreads();
    sm[tid] += t;
    __syncthreads();
  }
  int excl = sm[tid] - v;
  __syncthreads();
  sm[tid] = excl;
  __syncthreads();
  int pref = sm[blockIdx.x];

  int gid = blockIdx.x * 256 + tid;
  if (gid < N) offsets[gid] += pref;
  else if (gid == N) offsets[N] = E;
}

// atomic-free fill: slot = offsets[col] + rank (precomputed in prep)
__global__ __launch_bounds__(256) void fill_edges(const int* __restrict__ row,
                                                  const int* __restrict__ col,
                                                  const float* __restrict__ nrm,
                                                  const int* __restrict__ offsets,
                                                  const int* __restrict__ rank,
                                                  int2* __restrict__ emeta, int E) {
  int e = blockIdx.x * 256 + threadIdx.x;
  if (e >= E) return;
  int c = col[e];
  int idx = offsets[c] + rank[e];
  float s = (1.0f - ALPHA) * nrm[e];
  emeta[idx] = make_int2(row[e], __float_as_int(s));
}

// ---------------- fused gather + GEMM ----------------
// Phase 1 (R10/11-proven shfl form, 49us): bulk-load 64 edge metas per lane
// (coalesced), broadcast via shfl (ds_bpermute ~120cy, off the vmem queue);
// 8-edge unroll with 8 independent accumulator chains.
// Phase 2: 16x128 @ 128x128^T bf16 MFMA from LDS tile + L2-resident global Wb.
__global__ __launch_bounds__(256) void gather_gemm(const unsigned* __restrict__ xb,
                                                   const float* __restrict__ x0,
                                                   const int* __restrict__ offs,
                                                   const int2* __restrict__ emeta,
                                                   const short* __restrict__ Wb,
                                                   float* __restrict__ out, int N) {
  __shared__ unsigned short hb[16][136];
  const int tid = threadIdx.x;
  const int lane = tid & 63;
  const int wave = tid >> 6;
  const int row0 = blockIdx.x * 16;

  for (int q = 0; q < 4; ++q) {
    const int lr = wave * 4 + q;
    const int n = row0 + lr;
    unsigned packed = 0;
    if (n < N) {
      int s = offs[n], t = offs[n + 1];
      float accx[8], accy[8];
#pragma unroll
      for (int j = 0; j < 8; ++j) { accx[j] = 0.0f; accy[j] = 0.0f; }
      for (int base = s; base < t; base += 64) {
        int r = 0;
        float sc = 0.0f;
        if (base + lane < t) {
          int2 m = emeta[base + lane];
          r = m.x;
          sc = __int_as_float(m.y);
        }
        int cnt = t - base;
        if (cnt > 64) cnt = 64;
        int cnt8 = (cnt + 7) & ~7;
        for (int i = 0; i < cnt8; i += 8) {
#pragma unroll
          for (int j = 0; j < 8; ++j) {
            int rj = __shfl(r, i + j);
            float sj = __shfl(sc, i + j);
            unsigned u = xb[(size_t)rj * (DIM / 2) + lane];
            accx[j] += sj * __uint_as_float(u << 16);
            accy[j] += sj * __uint_as_float(u & 0xffff0000u);
          }
        }
      }
      float sx = ((accx[0] + accx[1]) + (accx[2] + accx[3])) +
                 ((accx[4] + accx[5]) + (accx[6] + accx[7]));
      float sy = ((accy[0] + accy[1]) + (accy[2] + accy[3])) +
                 ((accy[4] + accy[5]) + (accy[6] + accy[7]));
      float2 v0 = *(const float2*)(x0 + (size_t)n * DIM + 2 * lane);
      float hx = sx + ALPHA * v0.x;
      float hy = sy + ALPHA * v0.y;
      packed = (unsigned)f2bf(hx) | ((unsigned)f2bf(hy) << 16);
    }
    *(unsigned*)&hb[lr][2 * lane] = packed;
  }
  __syncthreads();

  const int arow = lane & 15;
  const int kg = (lane >> 4) * 8;
  short8v a[4];
#pragma unroll
  for (int s = 0; s < 4; ++s) a[s] = *(const short8v*)&hb[arow][s * 32 + kg];

#pragma unroll
  for (int j2 = 0; j2 < 2; ++j2) {
    const int jt = wave * 2 + j2;
    const int bcol = jt * 16 + (lane & 15);
    float4v acc = {0.0f, 0.0f, 0.0f, 0.0f};
#pragma unroll
    for (int s = 0; s < 4; ++s) {
      short8v b = *(const short8v*)(Wb + (size_t)bcol * DIM + s * 32 + kg);
      acc = __builtin_amdgcn_mfma_f32_16x16x32_bf16(a[s], b, acc, 0, 0, 0);
    }
    const int lr0 = (lane >> 4) << 2;
#pragma unroll
    for (int p = 0; p < 4; ++p) {
      int R = row0 + lr0 + p;
      if (R < N) {
        int c = jt * 16 + (lane & 15);
        float hv = __uint_as_float(((unsigned)hb[lr0 + p][c]) << 16);
        out[(size_t)R * DIM + c] = (1.0f - BETA) * hv + BETA * acc[p];
      }
    }
  }
}

// ---------------- mid-tier: count+rank, f32 gather + LDS-staged MFMA ----------------
__global__ __launch_bounds__(256) void count_edges(const int* __restrict__ col,
                                                   int* __restrict__ counts,
                                                   int* __restrict__ rank, int E) {
  int e = blockIdx.x * 256 + threadIdx.x;
  if (e < E) rank[e] = atomicAdd(&counts[col[e]], 1);
}

__global__ __launch_bounds__(256) void gather_nodes_f32(const float* __restrict__ x,
                                                        const float* __restrict__ x0,
                                                        const int* __restrict__ offs,
                                                        const int2* __restrict__ emeta,
                                                        float* __restrict__ h, int N) {
  int lane = threadIdx.x & 63;
  int gwave = blockIdx.x * 4 + (threadIdx.x >> 6);
  int nwaves = gridDim.x * 4;
  int dbase = 2 * lane;
  for (int n = gwave; n < N; n += nwaves) {
    int s = offs[n], t = offs[n + 1];
    float ax = 0, ay = 0, bx = 0, by = 0;
    for (int base = s; base < t; base += 64) {
      int r = 0;
      float sc = 0.0f;
      if (base + lane < t) {
        int2 m = emeta[base + lane];
        r = m.x;
        sc = __int_as_float(m.y);
      }
      int cnt = t - base;
      if (cnt > 64) cnt = 64;
      int cnt4 = (cnt + 3) & ~3;
      for (int i = 0; i < cnt4; i += 4) {
        int r0 = __shfl(r, i), r1 = __shfl(r, i + 1);
        int r2 = __shfl(r, i + 2), r3 = __shfl(r, i + 3);
        float s0 = __shfl(sc, i), s1 = __shfl(sc, i + 1);
        float s2 = __shfl(sc, i + 2), s3 = __shfl(sc, i + 3);
        float2 v0 = *(const float2*)(x + (size_t)r0 * DIM + dbase);
        float2 v1 = *(const float2*)(x + (size_t)r1 * DIM + dbase);
        float2 v2 = *(const float2*)(x + (size_t)r2 * DIM + dbase);
        float2 v3 = *(const float2*)(x + (size_t)r3 * DIM + dbase);
        ax += s0 * v0.x; ay += s0 * v0.y;
        bx += s1 * v1.x; by += s1 * v1.y;
        ax += s2 * v2.x; ay += s2 * v2.y;
        bx += s3 * v3.x; by += s3 * v3.y;
      }
    }
    float2 v0 = *(const float2*)(x0 + (size_t)n * DIM + dbase);
    float2 hv;
    hv.x = (ax + bx) + ALPHA * v0.x;
    hv.y = (ay + by) + ALPHA * v0.y;
    *(float2*)(h + (size_t)n * DIM + dbase) = hv;
  }
}

__global__ __launch_bounds__(256) void final_mfma(const float* __restrict__ W,
                                                  float* __restrict__ out, int N) {
  __shared__ short W_s[128][136];
  __shared__ short h_s[64][136];
  const int tid = threadIdx.x;
  const int lane = tid & 63;
  const int wave = tid >> 6;
  const int row0 = blockIdx.x * 64;

  for (int idx = tid; idx < 128 * 32; idx += 256) {
    int r = idx >> 5, c4 = idx & 31;
    float4 v = ((const float4*)(W + (size_t)r * DIM))[c4];
    *(short4*)&W_s[r][c4 * 4] = make_short4((short)f2bf(v.x), (short)f2bf(v.y),
                                            (short)f2bf(v.z), (short)f2bf(v.w));
  }
  for (int idx = tid; idx < 64 * 32; idx += 256) {
    int r = idx >> 5, c4 = idx & 31;
    int R = row0 + r;
    short4 sv = make_short4(0, 0, 0, 0);
    if (R < N) {
      float4 v = ((const float4*)(out + (size_t)R * DIM))[c4];
      sv = make_short4((short)f2bf(v.x), (short)f2bf(v.y), (short)f2bf(v.z),
                       (short)f2bf(v.w));
    }
    *(short4*)&h_s[r][c4 * 4] = sv;
  }
  __syncthreads();

  const int wr0 = wave * 16;
  const int arow = wr0 + (lane & 15);
  const int kg = (lane >> 4) * 8;
  short8v a[4];
#pragma unroll
  for (int s = 0; s < 4; ++s) a[s] = *(const short8v*)&h_s[arow][s * 32 + kg];

#pragma unroll
  for (int jt = 0; jt < 8; ++jt) {
    const int bcol = jt * 16 + (lane & 15);
    float4v acc = {0.0f, 0.0f, 0.0f, 0.0f};
#pragma unroll
    for (int s = 0; s < 4; ++s) {
      short8v b = *(const short8v*)&W_s[bcol][s * 32 + kg];
      acc = __builtin_amdgcn_mfma_f32_16x16x32_bf16(a[s], b, acc, 0, 0, 0);
    }
    const int rbase = row0 + wr0 + ((lane >> 4) << 2);
#pragma unroll
    for (int p = 0; p < 4; ++p) {
      int R = rbase + p;
      if (R < N) {
        size_t off = (size_t)R * DIM + jt * 16 + (lane & 15);
        out[off] = (1.0f - BETA) * out[off] + BETA * acc[p];
      }
    }
  }
}

// ---------------- last-resort atomic fallback ----------------
__global__ __launch_bounds__(256) void init_h(const float* __restrict__ x0,
                                              float* __restrict__ h, int total4) {
  int i = blockIdx.x * 256 + threadIdx.x;
  if (i < total4) {
    float4 v = ((const float4*)x0)[i];
    v.x *= ALPHA; v.y *= ALPHA; v.z *= ALPHA; v.w *= ALPHA;
    ((float4*)h)[i] = v;
  }
}

__global__ __launch_bounds__(256) void scatter_edges(const float* __restrict__ x,
                                                     const int* __restrict__ row,
                                                     const int* __restrict__ col,
                                                     const float* __restrict__ nrm,
                                                     float* __restrict__ h, int E) {
  int gid = blockIdx.x * 256 + threadIdx.x;
  int e = gid >> 5;
  if (e >= E) return;
  int d4 = (gid & 31) << 2;
  int r = row[e];
  int c = col[e];
  float s = (1.0f - ALPHA) * nrm[e];
  const float4 v = *(const float4*)(x + (size_t)r * DIM + d4);
  float* dst = h + (size_t)c * DIM + d4;
  atomicAdd(dst + 0, s * v.x);
  atomicAdd(dst + 1, s * v.y);
  atomicAdd(dst + 2, s * v.z);
  atomicAdd(dst + 3, s * v.w);
}

extern "C" void kernel_launch(void* const* d_in, const int* in_sizes, int n_in,
                              void* d_out, int out_size, void* d_ws, size_t ws_size,
                              hipStream_t stream) {
  const float* x = (const float*)d_in[0];
  const float* x0 = (const float*)d_in[1];
  const int* ei = (const int*)d_in[2];
  const float* nrm = (const float*)d_in[3];
  const float* W = (const float*)d_in[4];
  float* out = (float*)d_out;

  const int N = in_sizes[0] / DIM;
  const int E = in_sizes[2] / 2;
  const int* row = ei;
  const int* col = ei + E;

  // ws: counts[N+1] | offsets[N+1] | blockSums[256] | rank[E] | emeta int2[E]
  //     | xb bf16[N*DIM] | Wb bf16[128*128]
  const size_t csrNeed =
      (size_t)(2 * (N + 1) + 256 + E) * sizeof(int) + (size_t)E * 8;
  const size_t fullNeed =
      csrNeed + (size_t)N * DIM * sizeof(short) + 128 * 128 * sizeof(short);

  const int eBlocks = (E + 255) / 256;
  const int nBlocks = (N + 255) / 256;
  const int n1Blocks = (N + 256) / 256;

  if (ws_size >= csrNeed && nBlocks <= 256) {
    int* counts = (int*)d_ws;
    int* offsets = counts + (N + 1);
    int* blockSums = offsets + (N + 1);
    int* rank = blockSums + 256;
    int2* emeta = (int2*)(rank + E);
    short* xb = (short*)(emeta + E);
    short* Wb = xb + (size_t)N * DIM;

    hipMemsetAsync(counts, 0, (size_t)(N + 1) * sizeof(int), stream);

    if (ws_size >= fullNeed) {
      const int total4 = N * DIM / 4;
      const int cvtXBlocks = (total4 + 255) / 256;
      const int prepBlocks = eBlocks + cvtXBlocks + 16;
      hipLaunchKernelGGL(prep, dim3(prepBlocks), dim3(256), 0, stream, col, counts, rank, x, xb,
                         W, Wb, E, total4, eBlocks, cvtXBlocks);
      hipLaunchKernelGGL(scan_blocks, dim3(nBlocks), dim3(256), 0, stream, counts, offsets,
                         blockSums, N);
      hipLaunchKernelGGL(scan_off, dim3(n1Blocks), dim3(256), 0, stream, offsets, blockSums, N, E,
                         nBlocks);
      hipLaunchKernelGGL(fill_edges, dim3(eBlocks), dim3(256), 0, stream, row, col, nrm, offsets,
                         rank, emeta, E);
      const int t16 = (N + 15) / 16;
      hipLaunchKernelGGL(gather_gemm, dim3(t16), dim3(256), 0, stream, (const unsigned*)xb, x0,
                         offsets, emeta, Wb, out, N);
    } else {
      hipLaunchKernelGGL(count_edges, dim3(eBlocks), dim3(256), 0, stream, col, counts, rank, E);
      hipLaunchKernelGGL(scan_blocks, dim3(nBlocks), dim3(256), 0, stream, counts, offsets,
                         blockSums, N);
      hipLaunchKernelGGL(scan_off, dim3(n1Blocks), dim3(256), 0, stream, offsets, blockSums, N, E,
                         nBlocks);
      hipLaunchKernelGGL(fill_edges, dim3(eBlocks), dim3(256), 0, stream, row, col, nrm, offsets,
                         rank, emeta, E);
      const int gBlocks = (N + 3) / 4;
      hipLaunchKernelGGL(gather_nodes_f32, dim3(gBlocks), dim3(256), 0, stream, x, x0, offsets,
                         emeta, out, N);
      hipLaunchKernelGGL(final_mfma, dim3((N + 63) / 64), dim3(256), 0, stream, W, out, N);
    }
  } else {
    int total4 = N * DIM / 4;
    hipLaunchKernelGGL(init_h, dim3((total4 + 255) / 256), dim3(256), 0, stream, x0, out, total4);
    long long threads = (long long)E * 32;
    hipLaunchKernelGGL(scatter_edges, dim3((int)((threads + 255) / 256)), dim3(256), 0, stream, x,
                       row, col, nrm, out, E);
    hipLaunchKernelGGL(final_mfma, dim3((N + 63) / 64), dim3(256), 0, stream, W, out, N);
  }
}